// Round 11
// baseline (142.910 us; speedup 1.0000x reference)
//
#include <hip/hip_runtime.h>
#include <math.h>

#define TLEN 2048
#define T2   4096
#define H2   2048
#define NBLK 512
#define NS   64                               // reduction spread slots
#define EPS32 1.1920928955078125e-07

// agent-scope atomic load: always reads the coherent copy
__device__ __forceinline__ double ld_acc(const double* p){
  return __hip_atomic_load(p, __ATOMIC_RELAXED, __HIP_MEMORY_SCOPE_AGENT);
}

// ---- pure counter grid barrier (512 co-resident blocks; distinct counter per
//      use). NO threadfence (r4 lesson: ~26us each): cross-block data moves
//      only through atomics (deposits) which are already at the coherent point.
__device__ __forceinline__ void gbar(unsigned* bar){
  __syncthreads();
  if (threadIdx.x == 0){
    __hip_atomic_fetch_add(bar, 1u, __ATOMIC_RELAXED, __HIP_MEMORY_SCOPE_AGENT);
    unsigned spins = 0;
    while (__hip_atomic_load(bar, __ATOMIC_RELAXED, __HIP_MEMORY_SCOPE_AGENT) < NBLK){
      if (++spins > (1u << 20)) break;        // safety valve: fail loud, not hung
      __builtin_amdgcn_s_sleep(8);
    }
  }
  __syncthreads();
}

// ---- radix-4 Stockham stages (256 thr, 2 butterflies/thread), twiddles in LDS.
//      Stage loop stays `unroll 1` (r6 lesson: full unroll -> scratch spills). ----
__device__ __forceinline__ void r4_stages(float2* src, float2* dst,
                                          const float2* twl, float sgn, int nst){
  const int tid = threadIdx.x;
  #pragma unroll 1
  for (int t = 0; t < nst; ++t){
    const int L = 2 << (2 * t);
    const int Lm = L - 1;
    #pragma unroll
    for (int bf = 0; bf < 2; ++bf){
      int idx = tid + (bf << 8);              // 0..511
      int q  = idx & Lm;
      int tb = idx - q;                       // p*L (<= 510)
      float2 a = src[idx];
      float2 b = src[idx + 512];
      float2 c = src[idx + 1024];
      float2 d = src[idx + 1536];
      float2 w1 = twl[2 * tb];
      float2 w2 = twl[4 * tb];
      float2 w3 = twl[6 * tb];
      float w1y = sgn * w1.y, w2y = sgn * w2.y, w3y = sgn * w3.y;
      float t0x = a.x + c.x, t0y = a.y + c.y;
      float t1x = a.x - c.x, t1y = a.y - c.y;
      float t2x = b.x + d.x, t2y = b.y + d.y;
      // fwd: -i*(b-d) = (y,-x); inv: +i*(b-d) = (-y,x)
      float t3x = sgn * (b.y - d.y);
      float t3y = -sgn * (b.x - d.x);
      float y0x = t0x + t2x, y0y = t0y + t2y;
      float y1x = t1x + t3x, y1y = t1y + t3y;
      float y2x = t0x - t2x, y2y = t0y - t2y;
      float y3x = t1x - t3x, y3y = t1y - t3y;
      int ob = q + (tb << 2);                 // q + 4*p*L
      dst[ob]         = make_float2(y0x, y0y);
      dst[ob + L]     = make_float2(y1x * w1.x - y1y * w1y, y1x * w1y + y1y * w1.x);
      dst[ob + 2 * L] = make_float2(y2x * w2.x - y2y * w2y, y2x * w2y + y2y * w2.x);
      dst[ob + 3 * L] = make_float2(y3x * w3.x - y3y * w3y, y3x * w3y + y3y * w3.x);
    }
    __syncthreads();
    float2* tt = src; src = dst; dst = tt;
  }
}

// ---- wave-64 shuffle sum ----
__device__ __forceinline__ double wred(double v){
  #pragma unroll
  for (int off = 32; off; off >>= 1) v += __shfl_down(v, off);
  return v;
}

// ---- r11: DEPOSIT reduction. Block partials -> atomicAdd into this block's
//      spread slot (blk&63; 128 B apart). 8-way contention instead of the old
//      512-way same-address fp64 RMW serialization (theorized ~60us invariant). ----
__device__ __forceinline__ void red9_dep(double a0, double a1, double a2, double a3,
                                         double a4, double a5, double a6, double a7,
                                         double a8, double* red, double* slot){
  const int tid = threadIdx.x, wave = tid >> 6, lane = tid & 63;
  double r;
  r = wred(a0); if (lane == 0) red[ 0 + wave] = r;
  r = wred(a1); if (lane == 0) red[ 4 + wave] = r;
  r = wred(a2); if (lane == 0) red[ 8 + wave] = r;
  r = wred(a3); if (lane == 0) red[12 + wave] = r;
  r = wred(a4); if (lane == 0) red[16 + wave] = r;
  r = wred(a5); if (lane == 0) red[20 + wave] = r;
  r = wred(a6); if (lane == 0) red[24 + wave] = r;
  r = wred(a7); if (lane == 0) red[28 + wave] = r;
  r = wred(a8); if (lane == 0) red[32 + wave] = r;
  __syncthreads();
  if (tid < 9)
    atomicAdd(&slot[tid], red[tid*4+0] + red[tid*4+1] + red[tid*4+2] + red[tid*4+3]);
}

// ---- r11: GATHER. One coalesced 8 KB read of the round's slot array (LLC-hot),
//      staged through LDS (bufA is dead scratch), 9 threads sum 64 values each.
//      Ends with __syncthreads: gath[] valid for all threads after return. ----
__device__ __forceinline__ void gather9(const double* srnd, double* lds, double* gath){
  const int tid = threadIdx.x;
  #pragma unroll
  for (int i = 0; i < 4; ++i)
    lds[tid + (i << 8)] = ld_acc(srnd + tid + (i << 8));   // coalesced 8B x 256
  __syncthreads();
  if (tid < 9){
    double s = 0.0;
    #pragma unroll 4
    for (int k = 0; k < NS; ++k) s += lds[k * 16 + tid];
    gath[tid] = s;
  }
  __syncthreads();
}

// ---- per-thread state is NAMED variables only; F lives in bufB ----
#define MODE_S(UXc, UYc, OMc, AFP, AP) {                       \
  float ox_ = sx - (UXc), oy_ = sy - (UYc);                    \
  float d_  = fj - (OMc);                                      \
  float den_ = 1.0f + 2000.0f * d_ * d_;                       \
  float nx_ = (Fx - ox_) / den_, ny_ = (Fy - oy_) / den_;      \
  float pw_ = nx_ * nx_ + ny_ * ny_;                           \
  AFP += (double)(fj * pw_);  AP += (double)pw_;               \
  float ddx_ = nx_ - (UXc), ddy_ = ny_ - (UYc);                \
  aD += (double)(ddx_ * ddx_ + ddy_ * ddy_);                   \
  (UXc) = nx_; (UYc) = ny_;                                    \
  sx = ox_ + nx_; sy = oy_ + ny_; }

#define BIN_S(PP, UX, UY) {                                    \
  int j = tid + ((PP) << 8);                                   \
  float2 Fv = bufB[j];                                         \
  float Fx = Fv.x, Fy = Fv.y;                                  \
  float fj = (float)j * (1.0f / 4096.0f);                      \
  float sx = UX.x + UX.y + UX.z + UX.w;                        \
  float sy = UY.x + UY.y + UY.z + UY.w;                        \
  MODE_S(UX.x, UY.x, om.x, aFP0, aP0)                          \
  MODE_S(UX.y, UY.y, om.y, aFP1, aP1)                          \
  MODE_S(UX.z, UY.z, om.z, aFP2, aP2)                          \
  MODE_S(UX.w, UY.w, om.w, aFP3, aP3) }

#define IT1(PP, UX, UY) { UX = make_float4(0.f,0.f,0.f,0.f);   \
                          UY = make_float4(0.f,0.f,0.f,0.f);   \
                          BIN_S(PP, UX, UY) }

// iter-5 mode-0 update; write U[j] (positive-half spectrum) into bufA
#define HERMU(PP, UX, UY) {                                    \
  int j = tid + ((PP) << 8);                                   \
  float vx, vy;                                                \
  if (act){                                                    \
    float2 Fv = bufB[j];                                       \
    float sx = UX.y + UX.z + UX.w;                             \
    float sy = UY.y + UY.z + UY.w;                             \
    float fj = (float)j * (1.0f / 4096.0f);                    \
    float dd = fj - om0;                                       \
    float den = 1.0f + 2000.0f * dd * dd;                      \
    vx = (Fv.x - sx) / den; vy = (Fv.y - sy) / den;            \
  } else { vx = UX.x; vy = UY.x; }                             \
  bufA[j] = make_float2(vx, vy); }

#define FOR8(M) M(0,ux0,uy0) M(1,ux1,uy1) M(2,ux2,uy2) M(3,ux3,uy3) \
                M(4,ux4,uy4) M(5,ux5,uy5) M(6,ux6,uy6) M(7,ux7,uy7)

// fused forward radix-2 from packed registers (sgn=+1); writes float4 at bufB[2p]
#define R2F(BF, ZA, ZB) {                                      \
  int p = tid + ((BF) << 8);                                   \
  float2 w = twl[2 * p];                                       \
  float dx = ZA.x - ZB.x, dy = ZA.y - ZB.y;                    \
  *reinterpret_cast<float4*>(&bufB[2 * p]) =                   \
    make_float4(ZA.x + ZB.x, ZA.y + ZB.y,                      \
                dx * w.x - dy * w.y, dx * w.y + dy * w.x); }

// fused inverse LAST stage (L=512 => tb=0, twiddle-free); y1,y2 only
#define ILAST(IDX, Y1, Y2) {                                   \
  float2 a = bufA[IDX];                                        \
  float2 bb = bufA[(IDX) + 512];                               \
  float2 c = bufA[(IDX) + 1024];                               \
  float2 d = bufA[(IDX) + 1536];                               \
  float t1x = a.x - c.x, t1y = a.y - c.y;                      \
  float t3x = -(bb.y - d.y), t3y = (bb.x - d.x);               \
  Y1 = make_float2(t1x + t3x, t1y + t3y);                      \
  float t0x = a.x + c.x, t0y = a.y + c.y;                      \
  float t2x = bb.x + d.x, t2y = bb.y + d.y;                    \
  Y2 = make_float2(t0x - t2x, t0y - t2y); }

// ---- boot kernel: fp64-accurate twiddles + zero sync(128B) + slots(32 KiB).
//      Kernel boundary = free coherence for k_main. ----
__global__ void k_boot(float2* __restrict__ tw, unsigned* __restrict__ zr){
  int gid = blockIdx.x * 256 + threadIdx.x;   // 0..3071
  double a = -6.283185307179586 * (double)gid / 4096.0;
  tw[gid] = make_float2((float)cos(a), (float)sin(a));
  #pragma unroll
  for (int i = 0; i < 3; ++i){                // (128 + 32768)/4 = 8224 words
    int idx = gid + i * 3072;
    if (idx < 8224) zr[idx] = 0u;
  }
}

// ==== half-size real-packed FFT pipeline, 256 thr; spread-slot reduction ====
// slots layout: double[4][NS][16] — one 8 KiB array per reduction round.
__global__ void __attribute__((amdgpu_flat_work_group_size(256, 256),
                               amdgpu_waves_per_eu(2, 2)))
k_main(const float* __restrict__ x, const float2* __restrict__ tw,
       unsigned* __restrict__ bar, double* __restrict__ slots,
       float* __restrict__ xh, float* __restrict__ xl){
  __shared__ float2 twl[3072];                // 24 KiB twiddles (LDS-resident)
  __shared__ float2 bufA[H2];                 // 16 KiB
  __shared__ float2 bufB[H2];                 // 16 KiB
  __shared__ double gath[9];                  // gathered grid sums
  const int tid = threadIdx.x;
  const int b = blockIdx.x & 7, ch = blockIdx.x >> 3;
  const float* xc = x + (size_t)b * TLEN * 64 + ch;
  double* myslot = slots + (blockIdx.x & (NS - 1)) * 16;   // + round*1024

  // ---- stage twiddles to LDS (12 coalesced loads/thread) ----
  #pragma unroll
  for (int i = 0; i < 12; ++i)
    twl[tid + (i << 8)] = tw[tid + (i << 8)];

  // ---- pack z[m]=fM[2m]+i*fM[2m+1] into 8 registers (x read ONCE; z2..z5
  //      double as the epilogue's x stash) ----
  float2 z0, z1, z2, z3, z4, z5, z6, z7;
  z0 = make_float2(xc[(size_t)(1023 - 2*tid) * 64], xc[(size_t)(1022 - 2*tid) * 64]);
  z1 = make_float2(xc[(size_t)( 511 - 2*tid) * 64], xc[(size_t)( 510 - 2*tid) * 64]);
  { int t = 2*tid;        z2 = make_float2(xc[(size_t)t*64], xc[(size_t)(t+1)*64]); }
  { int t = 2*tid + 512;  z3 = make_float2(xc[(size_t)t*64], xc[(size_t)(t+1)*64]); }
  { int t = 2*tid + 1024; z4 = make_float2(xc[(size_t)t*64], xc[(size_t)(t+1)*64]); }
  { int t = 2*tid + 1536; z5 = make_float2(xc[(size_t)t*64], xc[(size_t)(t+1)*64]); }
  z6 = make_float2(xc[(size_t)(2047 - 2*tid) * 64], xc[(size_t)(2046 - 2*tid) * 64]);
  z7 = make_float2(xc[(size_t)(1535 - 2*tid) * 64], xc[(size_t)(1534 - 2*tid) * 64]);
  __syncthreads();                            // twl visible

  // ---- forward FFT: fused radix-2 from registers (pairs (m, m+1024)) ----
  R2F(0, z0, z4)  R2F(1, z1, z5)  R2F(2, z2, z6)  R2F(3, z3, z7)
  __syncthreads();
  r4_stages(bufB, bufA, twl, 1.0f, 5);        // Z in bufA

  // ---- unpack to F[k] (k=0..2047) in bufB ----
  #pragma unroll
  for (int pp = 0; pp < 8; ++pp){
    int k = tid + (pp << 8);
    float2 A  = bufA[k];
    float2 Zm = bufA[(2048 - k) & 2047];
    float px = 0.5f * (A.x + Zm.x), py = 0.5f * (A.y - Zm.y);
    float qx = 0.5f * (A.x - Zm.x), qy = 0.5f * (A.y + Zm.y);
    float2 W = twl[k];
    bufB[k] = make_float2(px + W.x * qy + W.y * qx,
                          py - W.x * qx + W.y * qy);
  }
  __syncthreads();   // all Z reads done before bufA becomes scratch

  float4 ux0, ux1, ux2, ux3, ux4, ux5, ux6, ux7;
  float4 uy0, uy1, uy2, uy3, uy4, uy5, uy6, uy7;
  float4 om = make_float4(0.0f, 0.125f, 0.25f, 0.375f);

  // iter 1 (u starts at 0)
  {
    double aFP0=0,aFP1=0,aFP2=0,aFP3=0,aP0=0,aP1=0,aP2=0,aP3=0,aD=0;
    FOR8(IT1)
    red9_dep(aFP0,aFP1,aFP2,aFP3,aP0,aP1,aP2,aP3,aD, (double*)bufA, myslot);
  }

  // ---- iters 2..4: gbar -> gather slots -> omega in-block ----
  bool active = true;
  #pragma unroll 1
  for (int it = 0; it < 3; ++it){
    gbar(bar + it);
    gather9(slots + it * 1024, (double*)bufA, gath);
    if (active){
      if (gath[8] * (1.0 / 4096.0) + EPS32 > 5e-5){
        om.x = (float)(gath[0] / gath[4]);
        om.y = (float)(gath[1] / gath[5]);
        om.z = (float)(gath[2] / gath[6]);
        om.w = (float)(gath[3] / gath[7]);
      } else active = false;
    }
    if (active){
      double aFP0=0,aFP1=0,aFP2=0,aFP3=0,aP0=0,aP1=0,aP2=0,aP3=0,aD=0;
      FOR8(BIN_S)
      red9_dep(aFP0,aFP1,aFP2,aFP3,aP0,aP1,aP2,aP3,aD, (double*)bufA,
               myslot + (it + 1) * 1024);
    }
  }
  gbar(bar + 3);
  gather9(slots + 3 * 1024, (double*)bufA, gath);

  // ---- guarded iter-5 mode-0 update; U -> bufA; Z' -> bufB; inverse FFT ----
  {
    bool act = active && (gath[8] * (1.0 / 4096.0) + EPS32 > 5e-5);
    float om0 = (float)(gath[0] / gath[4]);   // uniform; used only under act
    FOR8(HERMU)                               // reads F (bufB), writes U (bufA)
    __syncthreads();
    #pragma unroll
    for (int pp = 0; pp < 8; ++pp){           // build Z' into bufB
      int k = tid + (pp << 8);
      float2 Zv;
      if (k == 0){
        float e = bufA[0].x + bufA[2047].x;   // Re U0 + Re U2047
        float o = bufA[0].x - bufA[2047].x;
        Zv = make_float2(e, o);
      } else {
        float2 A  = bufA[k];
        float2 Bm = bufA[2048 - k];           // U[2048-k]
        float ex = A.x + Bm.x, ey = A.y - Bm.y;   // A + conj(Bm)
        float dx = A.x - Bm.x, dy = A.y + Bm.y;   // A - conj(Bm)
        float2 W = twl[k];                    // O' = D * conj(W)
        float ox = dx * W.x + dy * W.y;
        float oy = dy * W.x - dx * W.y;
        Zv = make_float2(ex - oy, ey + ox);   // E' + i O'
      }
      bufB[k] = Zv;
    }
    __syncthreads();
    // inverse radix-2 (reads bufB, writes bufA), sgn=-1
    #pragma unroll
    for (int bf = 0; bf < 4; ++bf){
      int p = tid + (bf << 8);
      float2 a = bufB[p], bb = bufB[p + 1024];
      float2 w = twl[2 * p];
      float dx = a.x - bb.x, dy = a.y - bb.y;
      *reinterpret_cast<float4*>(&bufA[2 * p]) =
        make_float4(a.x + bb.x, a.y + bb.y,
                    dx * w.x + dy * w.y, -dx * w.y + dy * w.x);
    }
    __syncthreads();
    r4_stages(bufA, bufB, twl, -1.0f, 4);     // stages L=2..128; result in bufA
  }

  // ---- fused last inverse stage + epilogue (all from registers) ----
  {
    const float scale = 1.0f / 4096.0f;
    float2 y1a, y2a, y1b, y2b;
    ILAST(tid,       y1a, y2a)                // y1 -> z'[512+tid],  y2 -> z'[1024+tid]
    ILAST(tid + 256, y1b, y2b)                // y1 -> z'[768+tid],  y2 -> z'[1280+tid]
    #define STOUT(YV, T0, ZS) {                                \
      size_t o0 = ((size_t)(b * TLEN + (T0))) * 64 + ch;       \
      float l0 = YV.x * scale, l1 = YV.y * scale;              \
      xh[o0]      = ZS.x - l0;  xl[o0]      = l0;              \
      xh[o0 + 64] = ZS.y - l1;  xl[o0 + 64] = l1; }
    STOUT(y1a, 2*tid,        z2)
    STOUT(y1b, 2*tid + 512,  z3)
    STOUT(y2a, 2*tid + 1024, z4)
    STOUT(y2b, 2*tid + 1536, z5)
  }
}

extern "C" void kernel_launch(void* const* d_in, const int* in_sizes, int n_in,
                              void* d_out, int out_size, void* d_ws, size_t ws_size,
                              hipStream_t stream){
  const float* x = (const float*)d_in[0];
  float* out_xh = (float*)d_out;
  float* out_xl = out_xh + (size_t)8 * TLEN * 64;

  char* ws = (char*)d_ws;
  float2* tw    = (float2*)ws;                    // 24 KiB (3072 twiddles)
  char*   sync  = ws + 32768;                     // 128 B: 16 barrier counters
  unsigned* bar = (unsigned*)sync;
  double* slots = (double*)(sync + 128);          // 4 rounds x 64 slots x 16 dbl

  k_boot<<<12, 256, 0, stream>>>(tw, (unsigned*)sync);   // tw + zero sync+slots
  k_main<<<NBLK, 256, 0, stream>>>(x, tw, bar, slots, out_xh, out_xl);
}

// Round 12
// 135.366 us; speedup vs baseline: 1.0557x; 1.0557x over previous
//
#include <hip/hip_runtime.h>
#include <math.h>

#define TLEN 2048
#define T2   4096
#define H2   2048
#define NBLK 512
#define EPS32 1.1920928955078125e-07

// agent-scope atomic load: always reads the coherent copy
__device__ __forceinline__ double ld_acc(const double* p){
  return __hip_atomic_load(p, __ATOMIC_RELAXED, __HIP_MEMORY_SCOPE_AGENT);
}

// ---- pure counter grid barrier (512 co-resident blocks; distinct counter per
//      use). NO threadfence (r4 lesson: ~26us each). ----
__device__ __forceinline__ void gbar(unsigned* bar){
  __syncthreads();
  if (threadIdx.x == 0){
    __hip_atomic_fetch_add(bar, 1u, __ATOMIC_RELAXED, __HIP_MEMORY_SCOPE_AGENT);
    unsigned spins = 0;
    while (__hip_atomic_load(bar, __ATOMIC_RELAXED, __HIP_MEMORY_SCOPE_AGENT) < NBLK){
      if (++spins > (1u << 20)) break;        // safety valve: fail loud, not hung
      __builtin_amdgcn_s_sleep(8);
    }
  }
  __syncthreads();
}

// ---- register butterflies ----
// r2: E = ZA+ZB; O = (ZA-ZB)*W^sgn
#define R2REG(ZA, ZB, W, SGN, E, O) {                           \
  float wy_ = (SGN) * W.y;                                      \
  E = make_float2(ZA.x + ZB.x, ZA.y + ZB.y);                    \
  float dx_ = ZA.x - ZB.x, dy_ = ZA.y - ZB.y;                   \
  O = make_float2(dx_ * W.x - dy_ * wy_, dx_ * wy_ + dy_ * W.x); }

// r4: inputs A,B,C,D; outputs Y0..Y3 with twiddles W1..W3 applied (Y0 free)
#define R4REG(A, B, C, D, W1, W2, W3, SGN, Y0, Y1, Y2, Y3) {    \
  float w1y_ = (SGN)*W1.y, w2y_ = (SGN)*W2.y, w3y_ = (SGN)*W3.y;\
  float t0x = A.x + C.x, t0y = A.y + C.y;                       \
  float t1x = A.x - C.x, t1y = A.y - C.y;                       \
  float t2x = B.x + D.x, t2y = B.y + D.y;                       \
  float t3x = (SGN) * (B.y - D.y), t3y = -(SGN) * (B.x - D.x);  \
  Y0 = make_float2(t0x + t2x, t0y + t2y);                       \
  float y1x = t1x + t3x, y1y = t1y + t3y;                       \
  float y2x = t0x - t2x, y2y = t0y - t2y;                       \
  float y3x = t1x - t3x, y3y = t1y - t3y;                       \
  Y1 = make_float2(y1x*W1.x - y1y*w1y_, y1x*w1y_ + y1y*W1.x);   \
  Y2 = make_float2(y2x*W2.x - y2y*w2y_, y2x*w2y_ + y2y*W2.x);   \
  Y3 = make_float2(y3x*W3.x - y3y*w3y_, y3x*w3y_ + y3y*W3.x); }

// ---- fused r2 + r4(L=2) entirely in registers (r12). Thread t holds z[p],
//      p = t+256c (c=0..7). r2 pairs (p,p+1024) -> evens/odds are exactly the
//      L=2 quads (tb=2t, twiddles twl[4t],[8t],[12t]); 8 outputs contiguous at
//      [8t, 8t+8) -> 4 float4 stores. One LDS round-trip replaces two. ----
__device__ __forceinline__ void fused2(float2 z0, float2 z1, float2 z2, float2 z3,
                                       float2 z4, float2 z5, float2 z6, float2 z7,
                                       const float2* twl, float sgn, float2* dst){
  const int tid = threadIdx.x;
  float2 wa = twl[2*tid], wb = twl[2*tid+512], wc = twl[2*tid+1024], wd = twl[2*tid+1536];
  float2 e0,o0,e1,o1,e2,o2,e3,o3;
  R2REG(z0, z4, wa, sgn, e0, o0)
  R2REG(z1, z5, wb, sgn, e1, o1)
  R2REG(z2, z6, wc, sgn, e2, o2)
  R2REG(z3, z7, wd, sgn, e3, o3)
  float2 w1 = twl[4*tid], w2 = twl[8*tid], w3 = twl[12*tid];
  float2 a0,a1,a2,a3, b0,b1,b2,b3;
  R4REG(e0, e1, e2, e3, w1, w2, w3, sgn, a0, a1, a2, a3)
  R4REG(o0, o1, o2, o3, w1, w2, w3, sgn, b0, b1, b2, b3)
  float4* d4 = reinterpret_cast<float4*>(dst + 8 * tid);
  d4[0] = make_float4(a0.x, a0.y, b0.x, b0.y);
  d4[1] = make_float4(a1.x, a1.y, b1.x, b1.y);
  d4[2] = make_float4(a2.x, a2.y, b2.x, b2.y);
  d4[3] = make_float4(a3.x, a3.y, b3.x, b3.y);
}

// ---- radix-4 LDS stages; L = 2<<(2*(first+t)). `unroll 1` (r6 spill lesson). ----
__device__ __forceinline__ void r4_stages(float2* src, float2* dst,
                                          const float2* twl, float sgn,
                                          int first, int cnt){
  const int tid = threadIdx.x;
  #pragma unroll 1
  for (int t = 0; t < cnt; ++t){
    const int L = 2 << (2 * (first + t));
    const int Lm = L - 1;
    #pragma unroll
    for (int bf = 0; bf < 2; ++bf){
      int idx = tid + (bf << 8);              // 0..511
      int q  = idx & Lm;
      int tb = idx - q;                       // p*L (<= 510)
      float2 a = src[idx];
      float2 b = src[idx + 512];
      float2 c = src[idx + 1024];
      float2 d = src[idx + 1536];
      float2 w1 = twl[2 * tb];
      float2 w2 = twl[4 * tb];
      float2 w3 = twl[6 * tb];
      float2 y0, y1, y2, y3;
      R4REG(a, b, c, d, w1, w2, w3, sgn, y0, y1, y2, y3)
      int ob = q + (tb << 2);                 // q + 4*p*L
      dst[ob]         = y0;
      dst[ob + L]     = y1;
      dst[ob + 2 * L] = y2;
      dst[ob + 3 * L] = y3;
    }
    __syncthreads();
    float2* tt = src; src = dst; dst = tt;
  }
}

// ---- wave-64 shuffle sum ----
__device__ __forceinline__ double wred(double v){
  #pragma unroll
  for (int off = 32; off; off >>= 1) v += __shfl_down(v, off);
  return v;
}

// ---- reduce 9 named doubles -> atomicAdd (agent scope) into accs; 4 waves.
//      Dedicated red[] scratch (bufA holds live Z/U data). ----
__device__ __forceinline__ void red9(double a0, double a1, double a2, double a3,
                                     double a4, double a5, double a6, double a7,
                                     double a8, double* red, double* accs){
  const int tid = threadIdx.x, wave = tid >> 6, lane = tid & 63;
  double r;
  r = wred(a0); if (lane == 0) red[ 0 + wave] = r;
  r = wred(a1); if (lane == 0) red[ 4 + wave] = r;
  r = wred(a2); if (lane == 0) red[ 8 + wave] = r;
  r = wred(a3); if (lane == 0) red[12 + wave] = r;
  r = wred(a4); if (lane == 0) red[16 + wave] = r;
  r = wred(a5); if (lane == 0) red[20 + wave] = r;
  r = wred(a6); if (lane == 0) red[24 + wave] = r;
  r = wred(a7); if (lane == 0) red[28 + wave] = r;
  r = wred(a8); if (lane == 0) red[32 + wave] = r;
  __syncthreads();
  if (tid < 9)
    atomicAdd(&accs[tid], red[tid*4+0] + red[tid*4+1] + red[tid*4+2] + red[tid*4+3]);
}

// ---- per-thread state: NAMED registers only. F in registers (r12): unpack
//      writes F[k] at k=tid+256pp — the exact index every BIN_S/HERMU read
//      uses, so F is thread-local for its entire life. ----
#define MODE_S(UXc, UYc, OMc, AFP, AP) {                       \
  float ox_ = sx - (UXc), oy_ = sy - (UYc);                    \
  float d_  = fj - (OMc);                                      \
  float den_ = 1.0f + 2000.0f * d_ * d_;                       \
  float nx_ = (Fx - ox_) / den_, ny_ = (Fy - oy_) / den_;      \
  float pw_ = nx_ * nx_ + ny_ * ny_;                           \
  AFP += (double)(fj * pw_);  AP += (double)pw_;               \
  float ddx_ = nx_ - (UXc), ddy_ = ny_ - (UYc);                \
  aD += (double)(ddx_ * ddx_ + ddy_ * ddy_);                   \
  (UXc) = nx_; (UYc) = ny_;                                    \
  sx = ox_ + nx_; sy = oy_ + ny_; }

#define BIN_S(PP, FV, UX, UY) {                                \
  float Fx = FV.x, Fy = FV.y;                                  \
  float fj = (float)(tid + ((PP) << 8)) * (1.0f / 4096.0f);    \
  float sx = UX.x + UX.y + UX.z + UX.w;                        \
  float sy = UY.x + UY.y + UY.z + UY.w;                        \
  MODE_S(UX.x, UY.x, om.x, aFP0, aP0)                          \
  MODE_S(UX.y, UY.y, om.y, aFP1, aP1)                          \
  MODE_S(UX.z, UY.z, om.z, aFP2, aP2)                          \
  MODE_S(UX.w, UY.w, om.w, aFP3, aP3) }

#define IT1(PP, FV, UX, UY) { UX = make_float4(0.f,0.f,0.f,0.f); \
                              UY = make_float4(0.f,0.f,0.f,0.f); \
                              BIN_S(PP, FV, UX, UY) }

// unpack Z (bufA) -> F register
#define FCOMP(PP, FV) {                                        \
  int k = tid + ((PP) << 8);                                   \
  float2 A  = bufA[k];                                         \
  float2 Zm = bufA[(2048 - k) & 2047];                         \
  float px = 0.5f * (A.x + Zm.x), py = 0.5f * (A.y - Zm.y);    \
  float qx = 0.5f * (A.x - Zm.x), qy = 0.5f * (A.y + Zm.y);    \
  float2 W = twl[k];                                           \
  FV = make_float2(px + W.x * qy + W.y * qx,                   \
                   py - W.x * qx + W.y * qy); }

// iter-5 mode-0 update; write U[j] into bufA (cross-thread for Z'-build)
#define HERMU(PP, FV, UX, UY) {                                \
  int j = tid + ((PP) << 8);                                   \
  float vx, vy;                                                \
  if (act){                                                    \
    float sx = UX.y + UX.z + UX.w;                             \
    float sy = UY.y + UY.z + UY.w;                             \
    float fj = (float)j * (1.0f / 4096.0f);                    \
    float dd = fj - om0;                                       \
    float den = 1.0f + 2000.0f * dd * dd;                      \
    vx = (FV.x - sx) / den; vy = (FV.y - sy) / den;            \
  } else { vx = UX.x; vy = UY.x; }                             \
  bufA[j] = make_float2(vx, vy); }

// build Z'[k] (k=tid+256*PP) into a register from U (bufA)
#define ZPCOMP(PP, ZV) {                                       \
  int k = tid + ((PP) << 8);                                   \
  if (k == 0){                                                 \
    float e = bufA[0].x + bufA[2047].x;                        \
    float o = bufA[0].x - bufA[2047].x;                        \
    ZV = make_float2(e, o);                                    \
  } else {                                                     \
    float2 A  = bufA[k];                                       \
    float2 Bm = bufA[2048 - k];                                \
    float ex = A.x + Bm.x, ey = A.y - Bm.y;                    \
    float dx = A.x - Bm.x, dy = A.y + Bm.y;                    \
    float2 W = twl[k];                                         \
    float ox = dx * W.x + dy * W.y;                            \
    float oy = dy * W.x - dx * W.y;                            \
    ZV = make_float2(ex - oy, ey + ox);                        \
  } }

#define FOR8F(M) M(0,f0,ux0,uy0) M(1,f1,ux1,uy1) M(2,f2,ux2,uy2) M(3,f3,ux3,uy3) \
                 M(4,f4,ux4,uy4) M(5,f5,ux5,uy5) M(6,f6,ux6,uy6) M(7,f7,ux7,uy7)

// fused inverse LAST stage (L=512 => tb=0, twiddle-free); y1,y2 only
#define ILAST(IDX, Y1, Y2) {                                   \
  float2 a = bufA[IDX];                                        \
  float2 bb = bufA[(IDX) + 512];                               \
  float2 c = bufA[(IDX) + 1024];                               \
  float2 d = bufA[(IDX) + 1536];                               \
  float t1x = a.x - c.x, t1y = a.y - c.y;                      \
  float t3x = -(bb.y - d.y), t3y = (bb.x - d.x);               \
  Y1 = make_float2(t1x + t3x, t1y + t3y);                      \
  float t0x = a.x + c.x, t0y = a.y + c.y;                      \
  float t2x = bb.x + d.x, t2y = bb.y + d.y;                    \
  Y2 = make_float2(t0x - t2x, t0y - t2y); }

// ---- boot kernel: fp64-accurate twiddles + zero sync area (bar + accs) ----
__global__ void k_boot(float2* __restrict__ tw, unsigned* __restrict__ syncz){
  int p = blockIdx.x * 256 + threadIdx.x;     // 0..3071
  double a = -6.283185307179586 * (double)p / 4096.0;
  tw[p] = make_float2((float)cos(a), (float)sin(a));
  if (blockIdx.x == 0 && threadIdx.x < 128) syncz[threadIdx.x] = 0u;
}

// ==== r12: phase-collapsed pipeline. r9/r11 lessons: time ~ #barrier phases.
// Forward: pack->regs, fused r2+L2 (regs), 4 LDS stages, F->regs. ~5 round trips.
// Iters: pure-register chains + red9 + somf broadcast.
// Inverse: HERMU->bufA, Z'+r2+L2 fused (regs)->bufB, 3 LDS stages, ILAST fused.
__global__ void __attribute__((amdgpu_flat_work_group_size(256, 256),
                               amdgpu_waves_per_eu(2, 2)))
k_main(const float* __restrict__ x, const float2* __restrict__ tw,
       unsigned* __restrict__ bar, double* __restrict__ accs,
       float* __restrict__ xh, float* __restrict__ xl){
  __shared__ float2 twl[3072];                // 24 KiB twiddles
  __shared__ float2 bufA[H2];                 // 16 KiB
  __shared__ float2 bufB[H2];                 // 16 KiB
  __shared__ double red[36];                  // reduction scratch (dedicated)
  __shared__ float somf[8];                   // omega/flag broadcast
  const int tid = threadIdx.x;
  const int b = blockIdx.x & 7, ch = blockIdx.x >> 3;
  const float* xc = x + (size_t)b * TLEN * 64 + ch;

  // ---- stage twiddles to LDS ----
  #pragma unroll
  for (int i = 0; i < 12; ++i)
    twl[tid + (i << 8)] = tw[tid + (i << 8)];

  // ---- pack z[m]=fM[2m]+i*fM[2m+1] (x read ONCE; z2..z5 = epilogue stash) ----
  float2 z0, z1, z2, z3, z4, z5, z6, z7;
  z0 = make_float2(xc[(size_t)(1023 - 2*tid) * 64], xc[(size_t)(1022 - 2*tid) * 64]);
  z1 = make_float2(xc[(size_t)( 511 - 2*tid) * 64], xc[(size_t)( 510 - 2*tid) * 64]);
  { int t = 2*tid;        z2 = make_float2(xc[(size_t)t*64], xc[(size_t)(t+1)*64]); }
  { int t = 2*tid + 512;  z3 = make_float2(xc[(size_t)t*64], xc[(size_t)(t+1)*64]); }
  { int t = 2*tid + 1024; z4 = make_float2(xc[(size_t)t*64], xc[(size_t)(t+1)*64]); }
  { int t = 2*tid + 1536; z5 = make_float2(xc[(size_t)t*64], xc[(size_t)(t+1)*64]); }
  z6 = make_float2(xc[(size_t)(2047 - 2*tid) * 64], xc[(size_t)(2046 - 2*tid) * 64]);
  z7 = make_float2(xc[(size_t)(1535 - 2*tid) * 64], xc[(size_t)(1534 - 2*tid) * 64]);
  __syncthreads();                            // twl visible

  // ---- forward FFT: fused r2+L2 in regs -> bufA; 4 LDS stages (L=8..512) ----
  fused2(z0, z1, z2, z3, z4, z5, z6, z7, twl, 1.0f, bufA);
  __syncthreads();
  r4_stages(bufA, bufB, twl, 1.0f, 1, 4);     // A->B->A->B->A: Z in bufA

  // ---- unpack to F REGISTERS (no LDS write-pass) ----
  float2 f0, f1, f2, f3, f4, f5, f6, f7;
  FCOMP(0, f0) FCOMP(1, f1) FCOMP(2, f2) FCOMP(3, f3)
  FCOMP(4, f4) FCOMP(5, f5) FCOMP(6, f6) FCOMP(7, f7)

  float4 ux0, ux1, ux2, ux3, ux4, ux5, ux6, ux7;
  float4 uy0, uy1, uy2, uy3, uy4, uy5, uy6, uy7;
  float4 om = make_float4(0.0f, 0.125f, 0.25f, 0.375f);

  // iter 1 (u starts at 0) — pure register compute
  {
    double aFP0=0,aFP1=0,aFP2=0,aFP3=0,aP0=0,aP1=0,aP2=0,aP3=0,aD=0;
    FOR8F(IT1)
    red9(aFP0,aFP1,aFP2,aFP3,aP0,aP1,aP2,aP3,aD, red, accs);
  }

  // ---- iters 2..4: gbar -> omega via per-block somf broadcast ----
  bool active = true;
  double* slot = accs;
  #pragma unroll 1
  for (int it = 0; it < 3; ++it){
    gbar(bar + it);
    if (tid < 4) somf[tid] = (float)(ld_acc(slot + tid) / ld_acc(slot + 4 + tid));
    if (tid == 7) somf[7] = (ld_acc(slot + 8) * (1.0/4096.0) + EPS32 > 5e-5) ? 1.f : 0.f;
    __syncthreads();
    if (active){
      if (somf[7] != 0.0f){
        om.x = somf[0]; om.y = somf[1]; om.z = somf[2]; om.w = somf[3];
      } else active = false;
    }
    if (active){
      double aFP0=0,aFP1=0,aFP2=0,aFP3=0,aP0=0,aP1=0,aP2=0,aP3=0,aD=0;
      FOR8F(BIN_S)
      red9(aFP0,aFP1,aFP2,aFP3,aP0,aP1,aP2,aP3,aD, red, slot + 9);
    }
    slot += 9;
  }
  gbar(bar + 3);
  if (tid == 0) somf[0] = (float)(ld_acc(slot) / ld_acc(slot + 4));
  if (tid == 7) somf[7] = (ld_acc(slot + 8) * (1.0/4096.0) + EPS32 > 5e-5) ? 1.f : 0.f;
  __syncthreads();

  // ---- guarded iter-5 mode-0 update; U -> bufA; fused Z'+r2+L2 -> bufB ----
  {
    bool act = active && (somf[7] != 0.0f);
    float om0 = somf[0];                      // uniform; used only under act
    FOR8F(HERMU)                              // writes U to bufA
    __syncthreads();
    float2 p0, p1, p2, p3, p4, p5, p6, p7;    // Z' in registers
    ZPCOMP(0, p0) ZPCOMP(1, p1) ZPCOMP(2, p2) ZPCOMP(3, p3)
    ZPCOMP(4, p4) ZPCOMP(5, p5) ZPCOMP(6, p6) ZPCOMP(7, p7)
    __syncthreads();                          // all U reads done before bufB?? (bufB untouched) — kept for bufA reuse safety below
    fused2(p0, p1, p2, p3, p4, p5, p6, p7, twl, -1.0f, bufB);
    __syncthreads();
    r4_stages(bufB, bufA, twl, -1.0f, 1, 3);  // B->A->B->A: result in bufA
  }

  // ---- fused last inverse stage + epilogue (all from registers) ----
  {
    const float scale = 1.0f / 4096.0f;
    float2 y1a, y2a, y1b, y2b;
    ILAST(tid,       y1a, y2a)                // y1 -> z'[512+tid],  y2 -> z'[1024+tid]
    ILAST(tid + 256, y1b, y2b)                // y1 -> z'[768+tid],  y2 -> z'[1280+tid]
    #define STOUT(YV, T0, ZS) {                                \
      size_t o0 = ((size_t)(b * TLEN + (T0))) * 64 + ch;       \
      float l0 = YV.x * scale, l1 = YV.y * scale;              \
      xh[o0]      = ZS.x - l0;  xl[o0]      = l0;              \
      xh[o0 + 64] = ZS.y - l1;  xl[o0 + 64] = l1; }
    STOUT(y1a, 2*tid,        z2)
    STOUT(y1b, 2*tid + 512,  z3)
    STOUT(y2a, 2*tid + 1024, z4)
    STOUT(y2b, 2*tid + 1536, z5)
  }
}

extern "C" void kernel_launch(void* const* d_in, const int* in_sizes, int n_in,
                              void* d_out, int out_size, void* d_ws, size_t ws_size,
                              hipStream_t stream){
  const float* x = (const float*)d_in[0];
  float* out_xh = (float*)d_out;
  float* out_xl = out_xh + (size_t)8 * TLEN * 64;

  char* ws = (char*)d_ws;
  float2* tw    = (float2*)ws;                    // 24 KiB (3072 twiddles)
  char*   sync  = ws + 32768;                     // bar (64B) + accs (288B)
  unsigned* bar = (unsigned*)sync;
  double* accs  = (double*)(sync + 128);          // 36 doubles

  k_boot<<<12, 256, 0, stream>>>(tw, (unsigned*)sync);
  k_main<<<NBLK, 256, 0, stream>>>(x, tw, bar, accs, out_xh, out_xl);
}

// Round 13
// 132.990 us; speedup vs baseline: 1.0746x; 1.0179x over previous
//
#include <hip/hip_runtime.h>
#include <math.h>

#define TLEN 2048
#define T2   4096
#define H2   2048
#define NBLK 512
#define EPS32 1.1920928955078125e-07

// agent-scope atomic load: always reads the coherent copy
__device__ __forceinline__ double ld_acc(const double* p){
  return __hip_atomic_load(p, __ATOMIC_RELAXED, __HIP_MEMORY_SCOPE_AGENT);
}

// ---- pure counter grid barrier (512 co-resident blocks; distinct counter per
//      use; zeroed by the 512-B memset each launch). NO threadfence (r4). ----
__device__ __forceinline__ void gbar(unsigned* bar){
  __syncthreads();
  if (threadIdx.x == 0){
    __hip_atomic_fetch_add(bar, 1u, __ATOMIC_RELAXED, __HIP_MEMORY_SCOPE_AGENT);
    unsigned spins = 0;
    while (__hip_atomic_load(bar, __ATOMIC_RELAXED, __HIP_MEMORY_SCOPE_AGENT) < NBLK){
      if (++spins > (1u << 21)) break;        // safety valve: fail loud, not hung
      __builtin_amdgcn_s_sleep(2);            // finer exit granularity (r13)
    }
  }
  __syncthreads();
}

// ---- register butterflies ----
#define R2REG(ZA, ZB, W, SGN, E, O) {                           \
  float wy_ = (SGN) * W.y;                                      \
  E = make_float2(ZA.x + ZB.x, ZA.y + ZB.y);                    \
  float dx_ = ZA.x - ZB.x, dy_ = ZA.y - ZB.y;                   \
  O = make_float2(dx_ * W.x - dy_ * wy_, dx_ * wy_ + dy_ * W.x); }

#define R4REG(A, B, C, D, W1, W2, W3, SGN, Y0, Y1, Y2, Y3) {    \
  float w1y_ = (SGN)*W1.y, w2y_ = (SGN)*W2.y, w3y_ = (SGN)*W3.y;\
  float t0x = A.x + C.x, t0y = A.y + C.y;                       \
  float t1x = A.x - C.x, t1y = A.y - C.y;                       \
  float t2x = B.x + D.x, t2y = B.y + D.y;                       \
  float t3x = (SGN) * (B.y - D.y), t3y = -(SGN) * (B.x - D.x);  \
  Y0 = make_float2(t0x + t2x, t0y + t2y);                       \
  float y1x = t1x + t3x, y1y = t1y + t3y;                       \
  float y2x = t0x - t2x, y2y = t0y - t2y;                       \
  float y3x = t1x - t3x, y3y = t1y - t3y;                       \
  Y1 = make_float2(y1x*W1.x - y1y*w1y_, y1x*w1y_ + y1y*W1.x);   \
  Y2 = make_float2(y2x*W2.x - y2y*w2y_, y2x*w2y_ + y2y*W2.x);   \
  Y3 = make_float2(y3x*W3.x - y3y*w3y_, y3x*w3y_ + y3y*W3.x); }

// ---- fused r2 + r4(L=2) entirely in registers (r12). 8 outputs contiguous at
//      [8t, 8t+8) -> 4 float4 stores. ----
__device__ __forceinline__ void fused2(float2 z0, float2 z1, float2 z2, float2 z3,
                                       float2 z4, float2 z5, float2 z6, float2 z7,
                                       const float2* twl, float sgn, float2* dst){
  const int tid = threadIdx.x;
  float2 wa = twl[2*tid], wb = twl[2*tid+512], wc = twl[2*tid+1024], wd = twl[2*tid+1536];
  float2 e0,o0,e1,o1,e2,o2,e3,o3;
  R2REG(z0, z4, wa, sgn, e0, o0)
  R2REG(z1, z5, wb, sgn, e1, o1)
  R2REG(z2, z6, wc, sgn, e2, o2)
  R2REG(z3, z7, wd, sgn, e3, o3)
  float2 w1 = twl[4*tid], w2 = twl[8*tid], w3 = twl[12*tid];
  float2 a0,a1,a2,a3, b0,b1,b2,b3;
  R4REG(e0, e1, e2, e3, w1, w2, w3, sgn, a0, a1, a2, a3)
  R4REG(o0, o1, o2, o3, w1, w2, w3, sgn, b0, b1, b2, b3)
  float4* d4 = reinterpret_cast<float4*>(dst + 8 * tid);
  d4[0] = make_float4(a0.x, a0.y, b0.x, b0.y);
  d4[1] = make_float4(a1.x, a1.y, b1.x, b1.y);
  d4[2] = make_float4(a2.x, a2.y, b2.x, b2.y);
  d4[3] = make_float4(a3.x, a3.y, b3.x, b3.y);
}

// ---- radix-4 LDS stages; L = 2<<(2*(first+t)). `unroll 1` (r6 spill lesson). ----
__device__ __forceinline__ void r4_stages(float2* src, float2* dst,
                                          const float2* twl, float sgn,
                                          int first, int cnt){
  const int tid = threadIdx.x;
  #pragma unroll 1
  for (int t = 0; t < cnt; ++t){
    const int L = 2 << (2 * (first + t));
    const int Lm = L - 1;
    #pragma unroll
    for (int bf = 0; bf < 2; ++bf){
      int idx = tid + (bf << 8);              // 0..511
      int q  = idx & Lm;
      int tb = idx - q;                       // p*L (<= 510)
      float2 a = src[idx];
      float2 b = src[idx + 512];
      float2 c = src[idx + 1024];
      float2 d = src[idx + 1536];
      float2 w1 = twl[2 * tb];
      float2 w2 = twl[4 * tb];
      float2 w3 = twl[6 * tb];
      float2 y0, y1, y2, y3;
      R4REG(a, b, c, d, w1, w2, w3, sgn, y0, y1, y2, y3)
      int ob = q + (tb << 2);                 // q + 4*p*L
      dst[ob]         = y0;
      dst[ob + L]     = y1;
      dst[ob + 2 * L] = y2;
      dst[ob + 3 * L] = y3;
    }
    __syncthreads();
    float2* tt = src; src = dst; dst = tt;
  }
}

// ---- wave-64 shuffle sum, f32 (r13: thread partials are f32 now) ----
__device__ __forceinline__ float wredf(float v){
  #pragma unroll
  for (int off = 32; off; off >>= 1) v += __shfl_down(v, off);
  return v;
}

// ---- reduce 9 f32 partials -> f64 atomicAdd into accs. Per-thread partials
//      cover only 8 bins (f32 exact to ~1e-7 rel); cross-lane in f32, cross-wave
//      and cross-block in f64 — more accurate than the reference's fp32 sums. ----
__device__ __forceinline__ void red9(float a0, float a1, float a2, float a3,
                                     float a4, float a5, float a6, float a7,
                                     float a8, float* redf, double* accs){
  const int tid = threadIdx.x, wave = tid >> 6, lane = tid & 63;
  float r;
  r = wredf(a0); if (lane == 0) redf[ 0 + wave] = r;
  r = wredf(a1); if (lane == 0) redf[ 4 + wave] = r;
  r = wredf(a2); if (lane == 0) redf[ 8 + wave] = r;
  r = wredf(a3); if (lane == 0) redf[12 + wave] = r;
  r = wredf(a4); if (lane == 0) redf[16 + wave] = r;
  r = wredf(a5); if (lane == 0) redf[20 + wave] = r;
  r = wredf(a6); if (lane == 0) redf[24 + wave] = r;
  r = wredf(a7); if (lane == 0) redf[28 + wave] = r;
  r = wredf(a8); if (lane == 0) redf[32 + wave] = r;
  __syncthreads();
  if (tid < 9){
    double s = (double)redf[tid*4+0] + (double)redf[tid*4+1]
             + (double)redf[tid*4+2] + (double)redf[tid*4+3];
    atomicAdd(&accs[tid], s);
  }
}

// ---- per-thread state: NAMED registers only; F in registers (r12) ----
#define MODE_S(UXc, UYc, OMc, AFP, AP) {                       \
  float ox_ = sx - (UXc), oy_ = sy - (UYc);                    \
  float d_  = fj - (OMc);                                      \
  float den_ = 1.0f + 2000.0f * d_ * d_;                       \
  float nx_ = (Fx - ox_) / den_, ny_ = (Fy - oy_) / den_;      \
  float pw_ = nx_ * nx_ + ny_ * ny_;                           \
  AFP += fj * pw_;  AP += pw_;                                 \
  float ddx_ = nx_ - (UXc), ddy_ = ny_ - (UYc);                \
  aD += ddx_ * ddx_ + ddy_ * ddy_;                             \
  (UXc) = nx_; (UYc) = ny_;                                    \
  sx = ox_ + nx_; sy = oy_ + ny_; }

#define BIN_S(PP, FV, UX, UY) {                                \
  float Fx = FV.x, Fy = FV.y;                                  \
  float fj = (float)(tid + ((PP) << 8)) * (1.0f / 4096.0f);    \
  float sx = UX.x + UX.y + UX.z + UX.w;                        \
  float sy = UY.x + UY.y + UY.z + UY.w;                        \
  MODE_S(UX.x, UY.x, om.x, aFP0, aP0)                          \
  MODE_S(UX.y, UY.y, om.y, aFP1, aP1)                          \
  MODE_S(UX.z, UY.z, om.z, aFP2, aP2)                          \
  MODE_S(UX.w, UY.w, om.w, aFP3, aP3) }

#define IT1(PP, FV, UX, UY) { UX = make_float4(0.f,0.f,0.f,0.f); \
                              UY = make_float4(0.f,0.f,0.f,0.f); \
                              BIN_S(PP, FV, UX, UY) }

// unpack Z (bufA) -> F register
#define FCOMP(PP, FV) {                                        \
  int k = tid + ((PP) << 8);                                   \
  float2 A  = bufA[k];                                         \
  float2 Zm = bufA[(2048 - k) & 2047];                         \
  float px = 0.5f * (A.x + Zm.x), py = 0.5f * (A.y - Zm.y);    \
  float qx = 0.5f * (A.x - Zm.x), qy = 0.5f * (A.y + Zm.y);    \
  float2 W = twl[k];                                           \
  FV = make_float2(px + W.x * qy + W.y * qx,                   \
                   py - W.x * qx + W.y * qy); }

// iter-5 mode-0 update; write U[j] into bufA (cross-thread for Z'-build)
#define HERMU(PP, FV, UX, UY) {                                \
  int j = tid + ((PP) << 8);                                   \
  float vx, vy;                                                \
  if (act){                                                    \
    float sx = UX.y + UX.z + UX.w;                             \
    float sy = UY.y + UY.z + UY.w;                             \
    float fj = (float)j * (1.0f / 4096.0f);                    \
    float dd = fj - om0;                                       \
    float den = 1.0f + 2000.0f * dd * dd;                      \
    vx = (FV.x - sx) / den; vy = (FV.y - sy) / den;            \
  } else { vx = UX.x; vy = UY.x; }                             \
  bufA[j] = make_float2(vx, vy); }

// build Z'[k] (k=tid+256*PP) into a register from U (bufA)
#define ZPCOMP(PP, ZV) {                                       \
  int k = tid + ((PP) << 8);                                   \
  if (k == 0){                                                 \
    float e = bufA[0].x + bufA[2047].x;                        \
    float o = bufA[0].x - bufA[2047].x;                        \
    ZV = make_float2(e, o);                                    \
  } else {                                                     \
    float2 A  = bufA[k];                                       \
    float2 Bm = bufA[2048 - k];                                \
    float ex = A.x + Bm.x, ey = A.y - Bm.y;                    \
    float dx = A.x - Bm.x, dy = A.y + Bm.y;                    \
    float2 W = twl[k];                                         \
    float ox = dx * W.x + dy * W.y;                            \
    float oy = dy * W.x - dx * W.y;                            \
    ZV = make_float2(ex - oy, ey + ox);                        \
  } }

#define FOR8F(M) M(0,f0,ux0,uy0) M(1,f1,ux1,uy1) M(2,f2,ux2,uy2) M(3,f3,ux3,uy3) \
                 M(4,f4,ux4,uy4) M(5,f5,ux5,uy5) M(6,f6,ux6,uy6) M(7,f7,ux7,uy7)

// fused inverse LAST stage (L=512 => tb=0, twiddle-free); y1,y2 only
#define ILAST(IDX, Y1, Y2) {                                   \
  float2 a = bufA[IDX];                                        \
  float2 bb = bufA[(IDX) + 512];                               \
  float2 c = bufA[(IDX) + 1024];                               \
  float2 d = bufA[(IDX) + 1536];                               \
  float t1x = a.x - c.x, t1y = a.y - c.y;                      \
  float t3x = -(bb.y - d.y), t3y = (bb.x - d.x);               \
  Y1 = make_float2(t1x + t3x, t1y + t3y);                      \
  float t0x = a.x + c.x, t0y = a.y + c.y;                      \
  float t2x = bb.x + d.x, t2y = bb.y + d.y;                    \
  Y2 = make_float2(t0x - t2x, t0y - t2y); }

// ==== r13: k_boot deleted. Twiddles generated in-kernel (12 sincosf/thread,
// fp64 angle, f32 sincos ~1 ulp — twiddle err ~3e-7 vs 24x absmax margin);
// thread accumulators f32 (reference itself accumulates fp32); boot dispatch
// replaced by a bare 512-B memset. ====
__global__ void __attribute__((amdgpu_flat_work_group_size(256, 256),
                               amdgpu_waves_per_eu(2, 2)))
k_main(const float* __restrict__ x, unsigned* __restrict__ bar,
       double* __restrict__ accs, float* __restrict__ xh, float* __restrict__ xl){
  __shared__ float2 twl[3072];                // 24 KiB twiddles
  __shared__ float2 bufA[H2];                 // 16 KiB
  __shared__ float2 bufB[H2];                 // 16 KiB
  __shared__ float redf[36];                  // reduction scratch (f32)
  __shared__ float somf[8];                   // omega/flag broadcast
  const int tid = threadIdx.x;
  const int b = blockIdx.x & 7, ch = blockIdx.x >> 3;
  const float* xc = x + (size_t)b * TLEN * 64 + ch;

  // ---- generate twiddles tw[p] = e^{-2pi i p/4096} into LDS ----
  #pragma unroll
  for (int i = 0; i < 12; ++i){
    int p = tid + (i << 8);
    float ang = (float)(-1.5339807878856412e-3 * (double)p);  // -2pi/4096 * p
    float s, c;
    sincosf(ang, &s, &c);
    twl[p] = make_float2(c, s);
  }

  // ---- pack z[m]=fM[2m]+i*fM[2m+1] (x read ONCE; z2..z5 = epilogue stash) ----
  float2 z0, z1, z2, z3, z4, z5, z6, z7;
  z0 = make_float2(xc[(size_t)(1023 - 2*tid) * 64], xc[(size_t)(1022 - 2*tid) * 64]);
  z1 = make_float2(xc[(size_t)( 511 - 2*tid) * 64], xc[(size_t)( 510 - 2*tid) * 64]);
  { int t = 2*tid;        z2 = make_float2(xc[(size_t)t*64], xc[(size_t)(t+1)*64]); }
  { int t = 2*tid + 512;  z3 = make_float2(xc[(size_t)t*64], xc[(size_t)(t+1)*64]); }
  { int t = 2*tid + 1024; z4 = make_float2(xc[(size_t)t*64], xc[(size_t)(t+1)*64]); }
  { int t = 2*tid + 1536; z5 = make_float2(xc[(size_t)t*64], xc[(size_t)(t+1)*64]); }
  z6 = make_float2(xc[(size_t)(2047 - 2*tid) * 64], xc[(size_t)(2046 - 2*tid) * 64]);
  z7 = make_float2(xc[(size_t)(1535 - 2*tid) * 64], xc[(size_t)(1534 - 2*tid) * 64]);
  __syncthreads();                            // twl visible

  // ---- forward FFT: fused r2+L2 in regs -> bufA; 4 LDS stages (L=8..512) ----
  fused2(z0, z1, z2, z3, z4, z5, z6, z7, twl, 1.0f, bufA);
  __syncthreads();
  r4_stages(bufA, bufB, twl, 1.0f, 1, 4);     // Z in bufA

  // ---- unpack to F REGISTERS ----
  float2 f0, f1, f2, f3, f4, f5, f6, f7;
  FCOMP(0, f0) FCOMP(1, f1) FCOMP(2, f2) FCOMP(3, f3)
  FCOMP(4, f4) FCOMP(5, f5) FCOMP(6, f6) FCOMP(7, f7)

  float4 ux0, ux1, ux2, ux3, ux4, ux5, ux6, ux7;
  float4 uy0, uy1, uy2, uy3, uy4, uy5, uy6, uy7;
  float4 om = make_float4(0.0f, 0.125f, 0.25f, 0.375f);

  // iter 1 (u starts at 0) — pure register compute, f32 partials
  {
    float aFP0=0,aFP1=0,aFP2=0,aFP3=0,aP0=0,aP1=0,aP2=0,aP3=0,aD=0;
    FOR8F(IT1)
    red9(aFP0,aFP1,aFP2,aFP3,aP0,aP1,aP2,aP3,aD, redf, accs);
  }

  // ---- iters 2..4: gbar -> omega via per-block somf broadcast ----
  bool active = true;
  double* slot = accs;
  #pragma unroll 1
  for (int it = 0; it < 3; ++it){
    gbar(bar + it);
    if (tid < 4) somf[tid] = (float)(ld_acc(slot + tid) / ld_acc(slot + 4 + tid));
    if (tid == 7) somf[7] = (ld_acc(slot + 8) * (1.0/4096.0) + EPS32 > 5e-5) ? 1.f : 0.f;
    __syncthreads();
    if (active){
      if (somf[7] != 0.0f){
        om.x = somf[0]; om.y = somf[1]; om.z = somf[2]; om.w = somf[3];
      } else active = false;
    }
    if (active){
      float aFP0=0,aFP1=0,aFP2=0,aFP3=0,aP0=0,aP1=0,aP2=0,aP3=0,aD=0;
      FOR8F(BIN_S)
      red9(aFP0,aFP1,aFP2,aFP3,aP0,aP1,aP2,aP3,aD, redf, slot + 9);
    }
    slot += 9;
  }
  gbar(bar + 3);
  if (tid == 0) somf[0] = (float)(ld_acc(slot) / ld_acc(slot + 4));
  if (tid == 7) somf[7] = (ld_acc(slot + 8) * (1.0/4096.0) + EPS32 > 5e-5) ? 1.f : 0.f;
  __syncthreads();

  // ---- guarded iter-5 mode-0 update; U -> bufA; fused Z'+r2+L2 -> bufB ----
  {
    bool act = active && (somf[7] != 0.0f);
    float om0 = somf[0];                      // uniform; used only under act
    FOR8F(HERMU)                              // writes U to bufA
    __syncthreads();
    float2 p0, p1, p2, p3, p4, p5, p6, p7;    // Z' in registers
    ZPCOMP(0, p0) ZPCOMP(1, p1) ZPCOMP(2, p2) ZPCOMP(3, p3)
    ZPCOMP(4, p4) ZPCOMP(5, p5) ZPCOMP(6, p6) ZPCOMP(7, p7)
    __syncthreads();
    fused2(p0, p1, p2, p3, p4, p5, p6, p7, twl, -1.0f, bufB);
    __syncthreads();
    r4_stages(bufB, bufA, twl, -1.0f, 1, 3);  // result in bufA
  }

  // ---- fused last inverse stage + epilogue (all from registers) ----
  {
    const float scale = 1.0f / 4096.0f;
    float2 y1a, y2a, y1b, y2b;
    ILAST(tid,       y1a, y2a)
    ILAST(tid + 256, y1b, y2b)
    #define STOUT(YV, T0, ZS) {                                \
      size_t o0 = ((size_t)(b * TLEN + (T0))) * 64 + ch;       \
      float l0 = YV.x * scale, l1 = YV.y * scale;              \
      xh[o0]      = ZS.x - l0;  xl[o0]      = l0;              \
      xh[o0 + 64] = ZS.y - l1;  xl[o0 + 64] = l1; }
    STOUT(y1a, 2*tid,        z2)
    STOUT(y1b, 2*tid + 512,  z3)
    STOUT(y2a, 2*tid + 1024, z4)
    STOUT(y2b, 2*tid + 1536, z5)
  }
}

extern "C" void kernel_launch(void* const* d_in, const int* in_sizes, int n_in,
                              void* d_out, int out_size, void* d_ws, size_t ws_size,
                              hipStream_t stream){
  const float* x = (const float*)d_in[0];
  float* out_xh = (float*)d_out;
  float* out_xl = out_xh + (size_t)8 * TLEN * 64;

  char* ws = (char*)d_ws;
  unsigned* bar = (unsigned*)ws;                  // 4 counters
  double* accs  = (double*)(ws + 128);            // 36 doubles

  hipMemsetAsync(ws, 0, 512, stream);             // zero bar + accs
  k_main<<<NBLK, 256, 0, stream>>>(x, bar, accs, out_xh, out_xl);
}

// Round 14
// 129.103 us; speedup vs baseline: 1.1069x; 1.0301x over previous
//
#include <hip/hip_runtime.h>
#include <math.h>

#define TLEN 2048
#define T2   4096
#define H2   2048
#define NBLK 512
#define EPS32 1.1920928955078125e-07

// agent-scope atomics: always at the coherent point (LLC)
__device__ __forceinline__ double ld_acc(const double* p){
  return __hip_atomic_load(p, __ATOMIC_RELAXED, __HIP_MEMORY_SCOPE_AGENT);
}
__device__ __forceinline__ unsigned ld_u32(const unsigned* p){
  return __hip_atomic_load(p, __ATOMIC_RELAXED, __HIP_MEMORY_SCOPE_AGENT);
}
__device__ __forceinline__ void st_u32(unsigned* p, unsigned v){
  __hip_atomic_store(p, v, __ATOMIC_RELAXED, __HIP_MEMORY_SCOPE_AGENT);
}

// ---- r14 tree barrier + fused omega broadcast. Arrival: 8 leaf counters
// (blk&7 = XCD residue, 128 B apart; max 64 same-line RMWs) -> root (8 RMWs).
// The GLOBAL-LAST block alone reads accs, computes omega+flag, publishes a
// 32-B record (4 om words, then release-store of flag). All blocks poll ONE
// line and pull omega from it — replaces 512-per-line RMW arrival + 4600
// same-line agent loads of the old gbar+somf path. tid0-only; caller wraps
// with __syncthreads (which drains this block's deposits: vmcnt0 precedes
// s_barrier, so deposit-completion < leaf RMW < root RMW < accs read). ----
__device__ void tree_sync_omega(unsigned* leaf, unsigned* root, unsigned* rec,
                                const double* slot, float* somf, int gid){
  unsigned old = __hip_atomic_fetch_add(leaf + (size_t)gid * 32, 1u,
                                        __ATOMIC_RELAXED, __HIP_MEMORY_SCOPE_AGENT);
  if (old == 63u){
    unsigned oldr = __hip_atomic_fetch_add(root, 1u,
                                           __ATOMIC_RELAXED, __HIP_MEMORY_SCOPE_AGENT);
    if (oldr == 7u){                          // global last: compute + publish
      double uD = ld_acc(slot + 8);
      float o0 = (float)(ld_acc(slot + 0) / ld_acc(slot + 4));
      float o1 = (float)(ld_acc(slot + 1) / ld_acc(slot + 5));
      float o2 = (float)(ld_acc(slot + 2) / ld_acc(slot + 6));
      float o3 = (float)(ld_acc(slot + 3) / ld_acc(slot + 7));
      unsigned fl = (uD * (1.0 / 4096.0) + EPS32 > 5e-5) ? 3u : 1u; // b0=ready b1=act
      st_u32(rec + 1, __float_as_uint(o0));
      st_u32(rec + 2, __float_as_uint(o1));
      st_u32(rec + 3, __float_as_uint(o2));
      st_u32(rec + 4, __float_as_uint(o3));
      __hip_atomic_store(rec, fl, __ATOMIC_RELEASE, __HIP_MEMORY_SCOPE_AGENT);
    }
  }
  unsigned f, spins = 0;
  while (((f = ld_u32(rec)) & 1u) == 0u){
    if (++spins > (1u << 22)) break;          // safety valve: fail loud, not hung
    __builtin_amdgcn_s_sleep(2);
  }
  somf[7] = (f & 2u) ? 1.f : 0.f;
  somf[0] = __uint_as_float(ld_u32(rec + 1)); // issued after flag load completes;
  somf[1] = __uint_as_float(ld_u32(rec + 2)); // writer's release ordered om first
  somf[2] = __uint_as_float(ld_u32(rec + 3));
  somf[3] = __uint_as_float(ld_u32(rec + 4));
}

// ---- register butterflies ----
#define R2REG(ZA, ZB, W, SGN, E, O) {                           \
  float wy_ = (SGN) * W.y;                                      \
  E = make_float2(ZA.x + ZB.x, ZA.y + ZB.y);                    \
  float dx_ = ZA.x - ZB.x, dy_ = ZA.y - ZB.y;                   \
  O = make_float2(dx_ * W.x - dy_ * wy_, dx_ * wy_ + dy_ * W.x); }

#define R4REG(A, B, C, D, W1, W2, W3, SGN, Y0, Y1, Y2, Y3) {    \
  float w1y_ = (SGN)*W1.y, w2y_ = (SGN)*W2.y, w3y_ = (SGN)*W3.y;\
  float t0x = A.x + C.x, t0y = A.y + C.y;                       \
  float t1x = A.x - C.x, t1y = A.y - C.y;                       \
  float t2x = B.x + D.x, t2y = B.y + D.y;                       \
  float t3x = (SGN) * (B.y - D.y), t3y = -(SGN) * (B.x - D.x);  \
  Y0 = make_float2(t0x + t2x, t0y + t2y);                       \
  float y1x = t1x + t3x, y1y = t1y + t3y;                       \
  float y2x = t0x - t2x, y2y = t0y - t2y;                       \
  float y3x = t1x - t3x, y3y = t1y - t3y;                       \
  Y1 = make_float2(y1x*W1.x - y1y*w1y_, y1x*w1y_ + y1y*W1.x);   \
  Y2 = make_float2(y2x*W2.x - y2y*w2y_, y2x*w2y_ + y2y*W2.x);   \
  Y3 = make_float2(y3x*W3.x - y3y*w3y_, y3x*w3y_ + y3y*W3.x); }

// ---- fused r2 + r4(L=2) in registers; 8 outputs contiguous -> 4 float4 ----
__device__ __forceinline__ void fused2(float2 z0, float2 z1, float2 z2, float2 z3,
                                       float2 z4, float2 z5, float2 z6, float2 z7,
                                       const float2* twl, float sgn, float2* dst){
  const int tid = threadIdx.x;
  float2 wa = twl[2*tid], wb = twl[2*tid+512], wc = twl[2*tid+1024], wd = twl[2*tid+1536];
  float2 e0,o0,e1,o1,e2,o2,e3,o3;
  R2REG(z0, z4, wa, sgn, e0, o0)
  R2REG(z1, z5, wb, sgn, e1, o1)
  R2REG(z2, z6, wc, sgn, e2, o2)
  R2REG(z3, z7, wd, sgn, e3, o3)
  float2 w1 = twl[4*tid], w2 = twl[8*tid], w3 = twl[12*tid];
  float2 a0,a1,a2,a3, b0,b1,b2,b3;
  R4REG(e0, e1, e2, e3, w1, w2, w3, sgn, a0, a1, a2, a3)
  R4REG(o0, o1, o2, o3, w1, w2, w3, sgn, b0, b1, b2, b3)
  float4* d4 = reinterpret_cast<float4*>(dst + 8 * tid);
  d4[0] = make_float4(a0.x, a0.y, b0.x, b0.y);
  d4[1] = make_float4(a1.x, a1.y, b1.x, b1.y);
  d4[2] = make_float4(a2.x, a2.y, b2.x, b2.y);
  d4[3] = make_float4(a3.x, a3.y, b3.x, b3.y);
}

// ---- radix-4 LDS stages; `unroll 1` (r6 spill lesson) ----
__device__ __forceinline__ void r4_stages(float2* src, float2* dst,
                                          const float2* twl, float sgn,
                                          int first, int cnt){
  const int tid = threadIdx.x;
  #pragma unroll 1
  for (int t = 0; t < cnt; ++t){
    const int L = 2 << (2 * (first + t));
    const int Lm = L - 1;
    #pragma unroll
    for (int bf = 0; bf < 2; ++bf){
      int idx = tid + (bf << 8);              // 0..511
      int q  = idx & Lm;
      int tb = idx - q;                       // p*L (<= 510)
      float2 a = src[idx];
      float2 b = src[idx + 512];
      float2 c = src[idx + 1024];
      float2 d = src[idx + 1536];
      float2 w1 = twl[2 * tb];
      float2 w2 = twl[4 * tb];
      float2 w3 = twl[6 * tb];
      float2 y0, y1, y2, y3;
      R4REG(a, b, c, d, w1, w2, w3, sgn, y0, y1, y2, y3)
      int ob = q + (tb << 2);                 // q + 4*p*L
      dst[ob]         = y0;
      dst[ob + L]     = y1;
      dst[ob + 2 * L] = y2;
      dst[ob + 3 * L] = y3;
    }
    __syncthreads();
    float2* tt = src; src = dst; dst = tt;
  }
}

// ---- wave-64 shuffle sum (f32 partials; 8-bin coverage keeps them exact) ----
__device__ __forceinline__ float wredf(float v){
  #pragma unroll
  for (int off = 32; off; off >>= 1) v += __shfl_down(v, off);
  return v;
}

// ---- reduce 9 f32 partials -> f64 atomicAdd into this round's accs slot ----
__device__ __forceinline__ void red9(float a0, float a1, float a2, float a3,
                                     float a4, float a5, float a6, float a7,
                                     float a8, float* redf, double* accs){
  const int tid = threadIdx.x, wave = tid >> 6, lane = tid & 63;
  float r;
  r = wredf(a0); if (lane == 0) redf[ 0 + wave] = r;
  r = wredf(a1); if (lane == 0) redf[ 4 + wave] = r;
  r = wredf(a2); if (lane == 0) redf[ 8 + wave] = r;
  r = wredf(a3); if (lane == 0) redf[12 + wave] = r;
  r = wredf(a4); if (lane == 0) redf[16 + wave] = r;
  r = wredf(a5); if (lane == 0) redf[20 + wave] = r;
  r = wredf(a6); if (lane == 0) redf[24 + wave] = r;
  r = wredf(a7); if (lane == 0) redf[28 + wave] = r;
  r = wredf(a8); if (lane == 0) redf[32 + wave] = r;
  __syncthreads();
  if (tid < 9){
    double s = (double)redf[tid*4+0] + (double)redf[tid*4+1]
             + (double)redf[tid*4+2] + (double)redf[tid*4+3];
    atomicAdd(&accs[tid], s);
  }
}

// ---- per-thread state: NAMED registers only; F in registers ----
#define MODE_S(UXc, UYc, OMc, AFP, AP) {                       \
  float ox_ = sx - (UXc), oy_ = sy - (UYc);                    \
  float d_  = fj - (OMc);                                      \
  float den_ = 1.0f + 2000.0f * d_ * d_;                       \
  float nx_ = (Fx - ox_) / den_, ny_ = (Fy - oy_) / den_;      \
  float pw_ = nx_ * nx_ + ny_ * ny_;                           \
  AFP += fj * pw_;  AP += pw_;                                 \
  float ddx_ = nx_ - (UXc), ddy_ = ny_ - (UYc);                \
  aD += ddx_ * ddx_ + ddy_ * ddy_;                             \
  (UXc) = nx_; (UYc) = ny_;                                    \
  sx = ox_ + nx_; sy = oy_ + ny_; }

#define BIN_S(PP, FV, UX, UY) {                                \
  float Fx = FV.x, Fy = FV.y;                                  \
  float fj = (float)(tid + ((PP) << 8)) * (1.0f / 4096.0f);    \
  float sx = UX.x + UX.y + UX.z + UX.w;                        \
  float sy = UY.x + UY.y + UY.z + UY.w;                        \
  MODE_S(UX.x, UY.x, om.x, aFP0, aP0)                          \
  MODE_S(UX.y, UY.y, om.y, aFP1, aP1)                          \
  MODE_S(UX.z, UY.z, om.z, aFP2, aP2)                          \
  MODE_S(UX.w, UY.w, om.w, aFP3, aP3) }

#define IT1(PP, FV, UX, UY) { UX = make_float4(0.f,0.f,0.f,0.f); \
                              UY = make_float4(0.f,0.f,0.f,0.f); \
                              BIN_S(PP, FV, UX, UY) }

#define FCOMP(PP, FV) {                                        \
  int k = tid + ((PP) << 8);                                   \
  float2 A  = bufA[k];                                         \
  float2 Zm = bufA[(2048 - k) & 2047];                         \
  float px = 0.5f * (A.x + Zm.x), py = 0.5f * (A.y - Zm.y);    \
  float qx = 0.5f * (A.x - Zm.x), qy = 0.5f * (A.y + Zm.y);    \
  float2 W = twl[k];                                           \
  FV = make_float2(px + W.x * qy + W.y * qx,                   \
                   py - W.x * qx + W.y * qy); }

#define HERMU(PP, FV, UX, UY) {                                \
  int j = tid + ((PP) << 8);                                   \
  float vx, vy;                                                \
  if (act){                                                    \
    float sx = UX.y + UX.z + UX.w;                             \
    float sy = UY.y + UY.z + UY.w;                             \
    float fj = (float)j * (1.0f / 4096.0f);                    \
    float dd = fj - om0;                                       \
    float den = 1.0f + 2000.0f * dd * dd;                      \
    vx = (FV.x - sx) / den; vy = (FV.y - sy) / den;            \
  } else { vx = UX.x; vy = UY.x; }                             \
  bufA[j] = make_float2(vx, vy); }

#define ZPCOMP(PP, ZV) {                                       \
  int k = tid + ((PP) << 8);                                   \
  if (k == 0){                                                 \
    float e = bufA[0].x + bufA[2047].x;                        \
    float o = bufA[0].x - bufA[2047].x;                        \
    ZV = make_float2(e, o);                                    \
  } else {                                                     \
    float2 A  = bufA[k];                                       \
    float2 Bm = bufA[2048 - k];                                \
    float ex = A.x + Bm.x, ey = A.y - Bm.y;                    \
    float dx = A.x - Bm.x, dy = A.y + Bm.y;                    \
    float2 W = twl[k];                                         \
    float ox = dx * W.x + dy * W.y;                            \
    float oy = dy * W.x - dx * W.y;                            \
    ZV = make_float2(ex - oy, ey + ox);                        \
  } }

#define FOR8F(M) M(0,f0,ux0,uy0) M(1,f1,ux1,uy1) M(2,f2,ux2,uy2) M(3,f3,ux3,uy3) \
                 M(4,f4,ux4,uy4) M(5,f5,ux5,uy5) M(6,f6,ux6,uy6) M(7,f7,ux7,uy7)

#define ILAST(IDX, Y1, Y2) {                                   \
  float2 a = bufA[IDX];                                        \
  float2 bb = bufA[(IDX) + 512];                               \
  float2 c = bufA[(IDX) + 1024];                               \
  float2 d = bufA[(IDX) + 1536];                               \
  float t1x = a.x - c.x, t1y = a.y - c.y;                      \
  float t3x = -(bb.y - d.y), t3y = (bb.x - d.x);               \
  Y1 = make_float2(t1x + t3x, t1y + t3y);                      \
  float t0x = a.x + c.x, t0y = a.y + c.y;                      \
  float t2x = bb.x + d.x, t2y = bb.y + d.y;                    \
  Y2 = make_float2(t0x - t2x, t0y - t2y); }

// ==== r14: tree barrier + fused omega broadcast; HW v_sin/v_cos twiddles
// (input in REVOLUTIONS, p/4096 exact in fp32 -> no argument-reduction error;
// reverts r13's libm sincosf regression). Everything else = r12 structure. ====
__global__ void __attribute__((amdgpu_flat_work_group_size(256, 256),
                               amdgpu_waves_per_eu(2, 2)))
k_main(const float* __restrict__ x, unsigned* __restrict__ leaf,
       unsigned* __restrict__ root, unsigned* __restrict__ rec,
       double* __restrict__ accs, float* __restrict__ xh, float* __restrict__ xl){
  __shared__ float2 twl[3072];                // 24 KiB twiddles
  __shared__ float2 bufA[H2];                 // 16 KiB
  __shared__ float2 bufB[H2];                 // 16 KiB
  __shared__ float redf[36];                  // reduction scratch (f32)
  __shared__ float somf[8];                   // omega/flag broadcast
  const int tid = threadIdx.x;
  const int b = blockIdx.x & 7, ch = blockIdx.x >> 3;
  const int gid = blockIdx.x & 7;             // leaf group = XCD residue
  const float* xc = x + (size_t)b * TLEN * 64 + ch;

  // ---- twiddles tw[p] = e^{-2pi i p/4096} via HW sin/cos (revolutions) ----
  #pragma unroll
  for (int i = 0; i < 12; ++i){
    int p = tid + (i << 8);
    float rev = (float)p * (-1.0f / 4096.0f);             // exact
    twl[p] = make_float2(__builtin_amdgcn_cosf(rev), __builtin_amdgcn_sinf(rev));
  }

  // ---- pack z[m]=fM[2m]+i*fM[2m+1] (x read ONCE; z2..z5 = epilogue stash) ----
  float2 z0, z1, z2, z3, z4, z5, z6, z7;
  z0 = make_float2(xc[(size_t)(1023 - 2*tid) * 64], xc[(size_t)(1022 - 2*tid) * 64]);
  z1 = make_float2(xc[(size_t)( 511 - 2*tid) * 64], xc[(size_t)( 510 - 2*tid) * 64]);
  { int t = 2*tid;        z2 = make_float2(xc[(size_t)t*64], xc[(size_t)(t+1)*64]); }
  { int t = 2*tid + 512;  z3 = make_float2(xc[(size_t)t*64], xc[(size_t)(t+1)*64]); }
  { int t = 2*tid + 1024; z4 = make_float2(xc[(size_t)t*64], xc[(size_t)(t+1)*64]); }
  { int t = 2*tid + 1536; z5 = make_float2(xc[(size_t)t*64], xc[(size_t)(t+1)*64]); }
  z6 = make_float2(xc[(size_t)(2047 - 2*tid) * 64], xc[(size_t)(2046 - 2*tid) * 64]);
  z7 = make_float2(xc[(size_t)(1535 - 2*tid) * 64], xc[(size_t)(1534 - 2*tid) * 64]);
  __syncthreads();                            // twl visible

  // ---- forward FFT: fused r2+L2 in regs -> bufA; 4 LDS stages ----
  fused2(z0, z1, z2, z3, z4, z5, z6, z7, twl, 1.0f, bufA);
  __syncthreads();
  r4_stages(bufA, bufB, twl, 1.0f, 1, 4);     // Z in bufA

  // ---- unpack to F REGISTERS ----
  float2 f0, f1, f2, f3, f4, f5, f6, f7;
  FCOMP(0, f0) FCOMP(1, f1) FCOMP(2, f2) FCOMP(3, f3)
  FCOMP(4, f4) FCOMP(5, f5) FCOMP(6, f6) FCOMP(7, f7)

  float4 ux0, ux1, ux2, ux3, ux4, ux5, ux6, ux7;
  float4 uy0, uy1, uy2, uy3, uy4, uy5, uy6, uy7;
  float4 om = make_float4(0.0f, 0.125f, 0.25f, 0.375f);

  // iter 1 (u starts at 0) — pure register compute
  {
    float aFP0=0,aFP1=0,aFP2=0,aFP3=0,aP0=0,aP1=0,aP2=0,aP3=0,aD=0;
    FOR8F(IT1)
    red9(aFP0,aFP1,aFP2,aFP3,aP0,aP1,aP2,aP3,aD, redf, accs);
  }

  // ---- iters 2..4: tree barrier + record-broadcast omega ----
  bool active = true;
  #pragma unroll 1
  for (int it = 0; it < 3; ++it){
    __syncthreads();                          // drain this block's deposits
    if (tid == 0)
      tree_sync_omega(leaf + it * 256, root + it * 32, rec + it * 32,
                      accs + it * 16, somf, gid);
    __syncthreads();                          // somf visible to all
    if (active){
      if (somf[7] != 0.0f){
        om.x = somf[0]; om.y = somf[1]; om.z = somf[2]; om.w = somf[3];
      } else active = false;
    }
    if (active){
      float aFP0=0,aFP1=0,aFP2=0,aFP3=0,aP0=0,aP1=0,aP2=0,aP3=0,aD=0;
      FOR8F(BIN_S)
      red9(aFP0,aFP1,aFP2,aFP3,aP0,aP1,aP2,aP3,aD, redf, accs + (it + 1) * 16);
    }
  }
  __syncthreads();
  if (tid == 0)
    tree_sync_omega(leaf + 3 * 256, root + 3 * 32, rec + 3 * 32,
                    accs + 3 * 16, somf, gid);
  __syncthreads();

  // ---- guarded iter-5 mode-0 update; U -> bufA; fused Z'+r2+L2 -> bufB ----
  {
    bool act = active && (somf[7] != 0.0f);
    float om0 = somf[0];                      // uniform; used only under act
    FOR8F(HERMU)                              // writes U to bufA
    __syncthreads();
    float2 p0, p1, p2, p3, p4, p5, p6, p7;    // Z' in registers
    ZPCOMP(0, p0) ZPCOMP(1, p1) ZPCOMP(2, p2) ZPCOMP(3, p3)
    ZPCOMP(4, p4) ZPCOMP(5, p5) ZPCOMP(6, p6) ZPCOMP(7, p7)
    __syncthreads();
    fused2(p0, p1, p2, p3, p4, p5, p6, p7, twl, -1.0f, bufB);
    __syncthreads();
    r4_stages(bufB, bufA, twl, -1.0f, 1, 3);  // result in bufA
  }

  // ---- fused last inverse stage + epilogue (all from registers) ----
  {
    const float scale = 1.0f / 4096.0f;
    float2 y1a, y2a, y1b, y2b;
    ILAST(tid,       y1a, y2a)
    ILAST(tid + 256, y1b, y2b)
    #define STOUT(YV, T0, ZS) {                                \
      size_t o0 = ((size_t)(b * TLEN + (T0))) * 64 + ch;       \
      float l0 = YV.x * scale, l1 = YV.y * scale;              \
      xh[o0]      = ZS.x - l0;  xl[o0]      = l0;              \
      xh[o0 + 64] = ZS.y - l1;  xl[o0 + 64] = l1; }
    STOUT(y1a, 2*tid,        z2)
    STOUT(y1b, 2*tid + 512,  z3)
    STOUT(y2a, 2*tid + 1024, z4)
    STOUT(y2b, 2*tid + 1536, z5)
  }
}

extern "C" void kernel_launch(void* const* d_in, const int* in_sizes, int n_in,
                              void* d_out, int out_size, void* d_ws, size_t ws_size,
                              hipStream_t stream){
  const float* x = (const float*)d_in[0];
  float* out_xh = (float*)d_out;
  float* out_xl = out_xh + (size_t)8 * TLEN * 64;

  // ws layout (all zeroed each launch):
  //   leaf:  4 rounds x 8 leaves x 128 B   = 4096 B   (leaf stride 32 u32)
  //   root:  4 rounds x 128 B              = 512 B    (stride 32 u32)
  //   rec:   4 rounds x 128 B              = 512 B    (stride 32 u32)
  //   accs:  4 rounds x 128 B (16 dbl)     = 512 B    (stride 16 dbl)
  char* ws = (char*)d_ws;
  unsigned* leaf = (unsigned*)ws;
  unsigned* root = (unsigned*)(ws + 4096);
  unsigned* rec  = (unsigned*)(ws + 4608);
  double*   accs = (double*)  (ws + 5120);

  hipMemsetAsync(ws, 0, 5632, stream);
  k_main<<<NBLK, 256, 0, stream>>>(x, leaf, root, rec, accs, out_xh, out_xl);
}

// Round 15
// 123.479 us; speedup vs baseline: 1.1574x; 1.0455x over previous
//
#include <hip/hip_runtime.h>
#include <math.h>

#define TLEN 2048
#define T2   4096
#define H2   2048
#define NBLK 512
#define EPS32 1.1920928955078125e-07

// agent-scope atomics: always at the coherent point (LLC)
__device__ __forceinline__ double ld_acc(const double* p){
  return __hip_atomic_load(p, __ATOMIC_RELAXED, __HIP_MEMORY_SCOPE_AGENT);
}
__device__ __forceinline__ unsigned ld_u32(const unsigned* p){
  return __hip_atomic_load(p, __ATOMIC_RELAXED, __HIP_MEMORY_SCOPE_AGENT);
}
__device__ __forceinline__ void st_u32(unsigned* p, unsigned v){
  __hip_atomic_store(p, v, __ATOMIC_RELAXED, __HIP_MEMORY_SCOPE_AGENT);
}

// ---- r14 tree barrier + fused omega broadcast (proven: -2us/barrier vs flat).
// Arrival: 8 leaf counters (128 B apart, 64 blocks each) -> root (8 RMWs).
// Global-last block computes omega once and publishes a 32-B record; all
// blocks poll ONE line. tid0-only; caller wraps with __syncthreads. ----
__device__ void tree_sync_omega(unsigned* leaf, unsigned* root, unsigned* rec,
                                const double* slot, float* somf, int gid){
  unsigned old = __hip_atomic_fetch_add(leaf + (size_t)gid * 32, 1u,
                                        __ATOMIC_RELAXED, __HIP_MEMORY_SCOPE_AGENT);
  if (old == 63u){
    unsigned oldr = __hip_atomic_fetch_add(root, 1u,
                                           __ATOMIC_RELAXED, __HIP_MEMORY_SCOPE_AGENT);
    if (oldr == 7u){                          // global last: compute + publish
      double uD = ld_acc(slot + 8);
      float o0 = (float)(ld_acc(slot + 0) / ld_acc(slot + 4));
      float o1 = (float)(ld_acc(slot + 1) / ld_acc(slot + 5));
      float o2 = (float)(ld_acc(slot + 2) / ld_acc(slot + 6));
      float o3 = (float)(ld_acc(slot + 3) / ld_acc(slot + 7));
      unsigned fl = (uD * (1.0 / 4096.0) + EPS32 > 5e-5) ? 3u : 1u; // b0=ready b1=act
      st_u32(rec + 1, __float_as_uint(o0));
      st_u32(rec + 2, __float_as_uint(o1));
      st_u32(rec + 3, __float_as_uint(o2));
      st_u32(rec + 4, __float_as_uint(o3));
      __hip_atomic_store(rec, fl, __ATOMIC_RELEASE, __HIP_MEMORY_SCOPE_AGENT);
    }
  }
  unsigned f, spins = 0;
  while (((f = ld_u32(rec)) & 1u) == 0u){
    if (++spins > (1u << 22)) break;          // safety valve: fail loud, not hung
    __builtin_amdgcn_s_sleep(2);
  }
  somf[7] = (f & 2u) ? 1.f : 0.f;
  somf[0] = __uint_as_float(ld_u32(rec + 1));
  somf[1] = __uint_as_float(ld_u32(rec + 2));
  somf[2] = __uint_as_float(ld_u32(rec + 3));
  somf[3] = __uint_as_float(ld_u32(rec + 4));
}

// ---- register butterflies ----
#define R2REG(ZA, ZB, W, SGN, E, O) {                           \
  float wy_ = (SGN) * W.y;                                      \
  E = make_float2(ZA.x + ZB.x, ZA.y + ZB.y);                    \
  float dx_ = ZA.x - ZB.x, dy_ = ZA.y - ZB.y;                   \
  O = make_float2(dx_ * W.x - dy_ * wy_, dx_ * wy_ + dy_ * W.x); }

#define R4REG(A, B, C, D, W1, W2, W3, SGN, Y0, Y1, Y2, Y3) {    \
  float w1y_ = (SGN)*W1.y, w2y_ = (SGN)*W2.y, w3y_ = (SGN)*W3.y;\
  float t0x = A.x + C.x, t0y = A.y + C.y;                       \
  float t1x = A.x - C.x, t1y = A.y - C.y;                       \
  float t2x = B.x + D.x, t2y = B.y + D.y;                       \
  float t3x = (SGN) * (B.y - D.y), t3y = -(SGN) * (B.x - D.x);  \
  Y0 = make_float2(t0x + t2x, t0y + t2y);                       \
  float y1x = t1x + t3x, y1y = t1y + t3y;                       \
  float y2x = t0x - t2x, y2y = t0y - t2y;                       \
  float y3x = t1x - t3x, y3y = t1y - t3y;                       \
  Y1 = make_float2(y1x*W1.x - y1y*w1y_, y1x*w1y_ + y1y*W1.x);   \
  Y2 = make_float2(y2x*W2.x - y2y*w2y_, y2x*w2y_ + y2y*W2.x);   \
  Y3 = make_float2(y3x*W3.x - y3y*w3y_, y3x*w3y_ + y3y*W3.x); }

// ---- fused r2 + r4(L=2) in registers; 8 outputs contiguous -> 4 float4 ----
__device__ __forceinline__ void fused2(float2 z0, float2 z1, float2 z2, float2 z3,
                                       float2 z4, float2 z5, float2 z6, float2 z7,
                                       const float2* twl, float sgn, float2* dst){
  const int tid = threadIdx.x;
  float2 wa = twl[2*tid], wb = twl[2*tid+512], wc = twl[2*tid+1024], wd = twl[2*tid+1536];
  float2 e0,o0,e1,o1,e2,o2,e3,o3;
  R2REG(z0, z4, wa, sgn, e0, o0)
  R2REG(z1, z5, wb, sgn, e1, o1)
  R2REG(z2, z6, wc, sgn, e2, o2)
  R2REG(z3, z7, wd, sgn, e3, o3)
  float2 w1 = twl[4*tid], w2 = twl[8*tid], w3 = twl[12*tid];
  float2 a0,a1,a2,a3, b0,b1,b2,b3;
  R4REG(e0, e1, e2, e3, w1, w2, w3, sgn, a0, a1, a2, a3)
  R4REG(o0, o1, o2, o3, w1, w2, w3, sgn, b0, b1, b2, b3)
  float4* d4 = reinterpret_cast<float4*>(dst + 8 * tid);
  d4[0] = make_float4(a0.x, a0.y, b0.x, b0.y);
  d4[1] = make_float4(a1.x, a1.y, b1.x, b1.y);
  d4[2] = make_float4(a2.x, a2.y, b2.x, b2.y);
  d4[3] = make_float4(a3.x, a3.y, b3.x, b3.y);
}

// ---- radix-4 LDS stages; `unroll 1` (r6 spill lesson) ----
__device__ __forceinline__ void r4_stages(float2* src, float2* dst,
                                          const float2* twl, float sgn,
                                          int first, int cnt){
  const int tid = threadIdx.x;
  #pragma unroll 1
  for (int t = 0; t < cnt; ++t){
    const int L = 2 << (2 * (first + t));
    const int Lm = L - 1;
    #pragma unroll
    for (int bf = 0; bf < 2; ++bf){
      int idx = tid + (bf << 8);              // 0..511
      int q  = idx & Lm;
      int tb = idx - q;                       // p*L (<= 510)
      float2 a = src[idx];
      float2 b = src[idx + 512];
      float2 c = src[idx + 1024];
      float2 d = src[idx + 1536];
      float2 w1 = twl[2 * tb];
      float2 w2 = twl[4 * tb];
      float2 w3 = twl[6 * tb];
      float2 y0, y1, y2, y3;
      R4REG(a, b, c, d, w1, w2, w3, sgn, y0, y1, y2, y3)
      int ob = q + (tb << 2);                 // q + 4*p*L
      dst[ob]         = y0;
      dst[ob + L]     = y1;
      dst[ob + 2 * L] = y2;
      dst[ob + 3 * L] = y3;
    }
    __syncthreads();
    float2* tt = src; src = dst; dst = tt;
  }
}

// ---- wave-64 shuffle sum (f32 partials; 8-bin coverage keeps them exact) ----
__device__ __forceinline__ float wredf(float v){
  #pragma unroll
  for (int off = 32; off; off >>= 1) v += __shfl_down(v, off);
  return v;
}

// ---- reduce 9 f32 partials -> f64 atomicAdd into this round's accs slot ----
__device__ __forceinline__ void red9(float a0, float a1, float a2, float a3,
                                     float a4, float a5, float a6, float a7,
                                     float a8, float* redf, double* accs){
  const int tid = threadIdx.x, wave = tid >> 6, lane = tid & 63;
  float r;
  r = wredf(a0); if (lane == 0) redf[ 0 + wave] = r;
  r = wredf(a1); if (lane == 0) redf[ 4 + wave] = r;
  r = wredf(a2); if (lane == 0) redf[ 8 + wave] = r;
  r = wredf(a3); if (lane == 0) redf[12 + wave] = r;
  r = wredf(a4); if (lane == 0) redf[16 + wave] = r;
  r = wredf(a5); if (lane == 0) redf[20 + wave] = r;
  r = wredf(a6); if (lane == 0) redf[24 + wave] = r;
  r = wredf(a7); if (lane == 0) redf[28 + wave] = r;
  r = wredf(a8); if (lane == 0) redf[32 + wave] = r;
  __syncthreads();
  if (tid < 9){
    double s = (double)redf[tid*4+0] + (double)redf[tid*4+1]
             + (double)redf[tid*4+2] + (double)redf[tid*4+3];
    atomicAdd(&accs[tid], s);
  }
}

// ---- per-thread state: NAMED registers only; F in registers.
// r15: precise f32 divide (v_div_scale/fmas/fixup ~11 instr) replaced by
// 1-instr v_rcp_f32 + mul — 2 divides/mode were ~30-40% of the whole VALU
// budget (128 mode-instances/thread). rcp err ~1ulp vs 24x absmax margin. ----
#define MODE_S(UXc, UYc, OMc, AFP, AP) {                       \
  float ox_ = sx - (UXc), oy_ = sy - (UYc);                    \
  float d_  = fj - (OMc);                                      \
  float rden_ = __builtin_amdgcn_rcpf(fmaf(2000.0f * d_, d_, 1.0f)); \
  float nx_ = (Fx - ox_) * rden_, ny_ = (Fy - oy_) * rden_;    \
  float pw_ = nx_ * nx_ + ny_ * ny_;                           \
  AFP += fj * pw_;  AP += pw_;                                 \
  float ddx_ = nx_ - (UXc), ddy_ = ny_ - (UYc);                \
  aD += ddx_ * ddx_ + ddy_ * ddy_;                             \
  (UXc) = nx_; (UYc) = ny_;                                    \
  sx = ox_ + nx_; sy = oy_ + ny_; }

#define BIN_S(PP, FV, UX, UY) {                                \
  float Fx = FV.x, Fy = FV.y;                                  \
  float fj = (float)(tid + ((PP) << 8)) * (1.0f / 4096.0f);    \
  float sx = UX.x + UX.y + UX.z + UX.w;                        \
  float sy = UY.x + UY.y + UY.z + UY.w;                        \
  MODE_S(UX.x, UY.x, om.x, aFP0, aP0)                          \
  MODE_S(UX.y, UY.y, om.y, aFP1, aP1)                          \
  MODE_S(UX.z, UY.z, om.z, aFP2, aP2)                          \
  MODE_S(UX.w, UY.w, om.w, aFP3, aP3) }

#define IT1(PP, FV, UX, UY) { UX = make_float4(0.f,0.f,0.f,0.f); \
                              UY = make_float4(0.f,0.f,0.f,0.f); \
                              BIN_S(PP, FV, UX, UY) }

#define FCOMP(PP, FV) {                                        \
  int k = tid + ((PP) << 8);                                   \
  float2 A  = bufA[k];                                         \
  float2 Zm = bufA[(2048 - k) & 2047];                         \
  float px = 0.5f * (A.x + Zm.x), py = 0.5f * (A.y - Zm.y);    \
  float qx = 0.5f * (A.x - Zm.x), qy = 0.5f * (A.y + Zm.y);    \
  float2 W = twl[k];                                           \
  FV = make_float2(px + W.x * qy + W.y * qx,                   \
                   py - W.x * qx + W.y * qy); }

#define HERMU(PP, FV, UX, UY) {                                \
  int j = tid + ((PP) << 8);                                   \
  float vx, vy;                                                \
  if (act){                                                    \
    float sx = UX.y + UX.z + UX.w;                             \
    float sy = UY.y + UY.z + UY.w;                             \
    float fj = (float)j * (1.0f / 4096.0f);                    \
    float dd = fj - om0;                                       \
    float rden = __builtin_amdgcn_rcpf(fmaf(2000.0f * dd, dd, 1.0f)); \
    vx = (FV.x - sx) * rden; vy = (FV.y - sy) * rden;          \
  } else { vx = UX.x; vy = UY.x; }                             \
  bufA[j] = make_float2(vx, vy); }

#define ZPCOMP(PP, ZV) {                                       \
  int k = tid + ((PP) << 8);                                   \
  if (k == 0){                                                 \
    float e = bufA[0].x + bufA[2047].x;                        \
    float o = bufA[0].x - bufA[2047].x;                        \
    ZV = make_float2(e, o);                                    \
  } else {                                                     \
    float2 A  = bufA[k];                                       \
    float2 Bm = bufA[2048 - k];                                \
    float ex = A.x + Bm.x, ey = A.y - Bm.y;                    \
    float dx = A.x - Bm.x, dy = A.y + Bm.y;                    \
    float2 W = twl[k];                                         \
    float ox = dx * W.x + dy * W.y;                            \
    float oy = dy * W.x - dx * W.y;                            \
    ZV = make_float2(ex - oy, ey + ox);                        \
  } }

#define FOR8F(M) M(0,f0,ux0,uy0) M(1,f1,ux1,uy1) M(2,f2,ux2,uy2) M(3,f3,ux3,uy3) \
                 M(4,f4,ux4,uy4) M(5,f5,ux5,uy5) M(6,f6,ux6,uy6) M(7,f7,ux7,uy7)

#define ILAST(IDX, Y1, Y2) {                                   \
  float2 a = bufA[IDX];                                        \
  float2 bb = bufA[(IDX) + 512];                               \
  float2 c = bufA[(IDX) + 1024];                               \
  float2 d = bufA[(IDX) + 1536];                               \
  float t1x = a.x - c.x, t1y = a.y - c.y;                      \
  float t3x = -(bb.y - d.y), t3y = (bb.x - d.x);               \
  Y1 = make_float2(t1x + t3x, t1y + t3y);                      \
  float t0x = a.x + c.x, t0y = a.y + c.y;                      \
  float t2x = bb.x + d.x, t2y = bb.y + d.y;                    \
  Y2 = make_float2(t0x - t2x, t0y - t2y); }

// ==== r15 = r14 structure + rcp-divide. HW v_sin/v_cos twiddles (revolutions,
// p/4096 exact). Tree barrier. F/u/z all in named registers. ====
__global__ void __attribute__((amdgpu_flat_work_group_size(256, 256),
                               amdgpu_waves_per_eu(2, 2)))
k_main(const float* __restrict__ x, unsigned* __restrict__ leaf,
       unsigned* __restrict__ root, unsigned* __restrict__ rec,
       double* __restrict__ accs, float* __restrict__ xh, float* __restrict__ xl){
  __shared__ float2 twl[3072];                // 24 KiB twiddles
  __shared__ float2 bufA[H2];                 // 16 KiB
  __shared__ float2 bufB[H2];                 // 16 KiB
  __shared__ float redf[36];                  // reduction scratch (f32)
  __shared__ float somf[8];                   // omega/flag broadcast
  const int tid = threadIdx.x;
  const int b = blockIdx.x & 7, ch = blockIdx.x >> 3;
  const int gid = blockIdx.x & 7;             // leaf group = XCD residue
  const float* xc = x + (size_t)b * TLEN * 64 + ch;

  // ---- twiddles tw[p] = e^{-2pi i p/4096} via HW sin/cos (revolutions) ----
  #pragma unroll
  for (int i = 0; i < 12; ++i){
    int p = tid + (i << 8);
    float rev = (float)p * (-1.0f / 4096.0f);             // exact
    twl[p] = make_float2(__builtin_amdgcn_cosf(rev), __builtin_amdgcn_sinf(rev));
  }

  // ---- pack z[m]=fM[2m]+i*fM[2m+1] (x read ONCE; z2..z5 = epilogue stash) ----
  float2 z0, z1, z2, z3, z4, z5, z6, z7;
  z0 = make_float2(xc[(size_t)(1023 - 2*tid) * 64], xc[(size_t)(1022 - 2*tid) * 64]);
  z1 = make_float2(xc[(size_t)( 511 - 2*tid) * 64], xc[(size_t)( 510 - 2*tid) * 64]);
  { int t = 2*tid;        z2 = make_float2(xc[(size_t)t*64], xc[(size_t)(t+1)*64]); }
  { int t = 2*tid + 512;  z3 = make_float2(xc[(size_t)t*64], xc[(size_t)(t+1)*64]); }
  { int t = 2*tid + 1024; z4 = make_float2(xc[(size_t)t*64], xc[(size_t)(t+1)*64]); }
  { int t = 2*tid + 1536; z5 = make_float2(xc[(size_t)t*64], xc[(size_t)(t+1)*64]); }
  z6 = make_float2(xc[(size_t)(2047 - 2*tid) * 64], xc[(size_t)(2046 - 2*tid) * 64]);
  z7 = make_float2(xc[(size_t)(1535 - 2*tid) * 64], xc[(size_t)(1534 - 2*tid) * 64]);
  __syncthreads();                            // twl visible

  // ---- forward FFT: fused r2+L2 in regs -> bufA; 4 LDS stages ----
  fused2(z0, z1, z2, z3, z4, z5, z6, z7, twl, 1.0f, bufA);
  __syncthreads();
  r4_stages(bufA, bufB, twl, 1.0f, 1, 4);     // Z in bufA

  // ---- unpack to F REGISTERS ----
  float2 f0, f1, f2, f3, f4, f5, f6, f7;
  FCOMP(0, f0) FCOMP(1, f1) FCOMP(2, f2) FCOMP(3, f3)
  FCOMP(4, f4) FCOMP(5, f5) FCOMP(6, f6) FCOMP(7, f7)

  float4 ux0, ux1, ux2, ux3, ux4, ux5, ux6, ux7;
  float4 uy0, uy1, uy2, uy3, uy4, uy5, uy6, uy7;
  float4 om = make_float4(0.0f, 0.125f, 0.25f, 0.375f);

  // iter 1 (u starts at 0) — pure register compute
  {
    float aFP0=0,aFP1=0,aFP2=0,aFP3=0,aP0=0,aP1=0,aP2=0,aP3=0,aD=0;
    FOR8F(IT1)
    red9(aFP0,aFP1,aFP2,aFP3,aP0,aP1,aP2,aP3,aD, redf, accs);
  }

  // ---- iters 2..4: tree barrier + record-broadcast omega ----
  bool active = true;
  #pragma unroll 1
  for (int it = 0; it < 3; ++it){
    __syncthreads();                          // drain this block's deposits
    if (tid == 0)
      tree_sync_omega(leaf + it * 256, root + it * 32, rec + it * 32,
                      accs + it * 16, somf, gid);
    __syncthreads();                          // somf visible to all
    if (active){
      if (somf[7] != 0.0f){
        om.x = somf[0]; om.y = somf[1]; om.z = somf[2]; om.w = somf[3];
      } else active = false;
    }
    if (active){
      float aFP0=0,aFP1=0,aFP2=0,aFP3=0,aP0=0,aP1=0,aP2=0,aP3=0,aD=0;
      FOR8F(BIN_S)
      red9(aFP0,aFP1,aFP2,aFP3,aP0,aP1,aP2,aP3,aD, redf, accs + (it + 1) * 16);
    }
  }
  __syncthreads();
  if (tid == 0)
    tree_sync_omega(leaf + 3 * 256, root + 3 * 32, rec + 3 * 32,
                    accs + 3 * 16, somf, gid);
  __syncthreads();

  // ---- guarded iter-5 mode-0 update; U -> bufA; fused Z'+r2+L2 -> bufB ----
  {
    bool act = active && (somf[7] != 0.0f);
    float om0 = somf[0];                      // uniform; used only under act
    FOR8F(HERMU)                              // writes U to bufA
    __syncthreads();
    float2 p0, p1, p2, p3, p4, p5, p6, p7;    // Z' in registers
    ZPCOMP(0, p0) ZPCOMP(1, p1) ZPCOMP(2, p2) ZPCOMP(3, p3)
    ZPCOMP(4, p4) ZPCOMP(5, p5) ZPCOMP(6, p6) ZPCOMP(7, p7)
    __syncthreads();
    fused2(p0, p1, p2, p3, p4, p5, p6, p7, twl, -1.0f, bufB);
    __syncthreads();
    r4_stages(bufB, bufA, twl, -1.0f, 1, 3);  // result in bufA
  }

  // ---- fused last inverse stage + epilogue (all from registers) ----
  {
    const float scale = 1.0f / 4096.0f;
    float2 y1a, y2a, y1b, y2b;
    ILAST(tid,       y1a, y2a)
    ILAST(tid + 256, y1b, y2b)
    #define STOUT(YV, T0, ZS) {                                \
      size_t o0 = ((size_t)(b * TLEN + (T0))) * 64 + ch;       \
      float l0 = YV.x * scale, l1 = YV.y * scale;              \
      xh[o0]      = ZS.x - l0;  xl[o0]      = l0;              \
      xh[o0 + 64] = ZS.y - l1;  xl[o0 + 64] = l1; }
    STOUT(y1a, 2*tid,        z2)
    STOUT(y1b, 2*tid + 512,  z3)
    STOUT(y2a, 2*tid + 1024, z4)
    STOUT(y2b, 2*tid + 1536, z5)
  }
}

extern "C" void kernel_launch(void* const* d_in, const int* in_sizes, int n_in,
                              void* d_out, int out_size, void* d_ws, size_t ws_size,
                              hipStream_t stream){
  const float* x = (const float*)d_in[0];
  float* out_xh = (float*)d_out;
  float* out_xl = out_xh + (size_t)8 * TLEN * 64;

  // ws layout (all zeroed each launch):
  //   leaf:  4 rounds x 8 leaves x 128 B   = 4096 B   (leaf stride 32 u32)
  //   root:  4 rounds x 128 B              = 512 B    (stride 32 u32)
  //   rec:   4 rounds x 128 B              = 512 B    (stride 32 u32)
  //   accs:  4 rounds x 128 B (16 dbl)     = 512 B    (stride 16 dbl)
  char* ws = (char*)d_ws;
  unsigned* leaf = (unsigned*)ws;
  unsigned* root = (unsigned*)(ws + 4096);
  unsigned* rec  = (unsigned*)(ws + 4608);
  double*   accs = (double*)  (ws + 5120);

  hipMemsetAsync(ws, 0, 5632, stream);
  k_main<<<NBLK, 256, 0, stream>>>(x, leaf, root, rec, accs, out_xh, out_xl);
}

// Round 16
// 118.688 us; speedup vs baseline: 1.2041x; 1.0404x over previous
//
#include <hip/hip_runtime.h>
#include <math.h>

#define NBLK 512
#define EPS32 1.1920928955078125e-07

// agent-scope atomics: always at the coherent point (LLC)
__device__ __forceinline__ double ld_acc(const double* p){
  return __hip_atomic_load(p, __ATOMIC_RELAXED, __HIP_MEMORY_SCOPE_AGENT);
}
__device__ __forceinline__ unsigned ld_u32(const unsigned* p){
  return __hip_atomic_load(p, __ATOMIC_RELAXED, __HIP_MEMORY_SCOPE_AGENT);
}
__device__ __forceinline__ void st_u32(unsigned* p, unsigned v){
  __hip_atomic_store(p, v, __ATOMIC_RELAXED, __HIP_MEMORY_SCOPE_AGENT);
}

// ---- r14 tree barrier + fused omega broadcast (proven -2us/barrier) ----
__device__ void tree_sync_omega(unsigned* leaf, unsigned* root, unsigned* rec,
                                const double* slot, float* somf, int gid){
  unsigned old = __hip_atomic_fetch_add(leaf + (size_t)gid * 32, 1u,
                                        __ATOMIC_RELAXED, __HIP_MEMORY_SCOPE_AGENT);
  if (old == 63u){
    unsigned oldr = __hip_atomic_fetch_add(root, 1u,
                                           __ATOMIC_RELAXED, __HIP_MEMORY_SCOPE_AGENT);
    if (oldr == 7u){                          // global last: compute + publish
      double uD = ld_acc(slot + 8);
      float o0 = (float)(ld_acc(slot + 0) / ld_acc(slot + 4));
      float o1 = (float)(ld_acc(slot + 1) / ld_acc(slot + 5));
      float o2 = (float)(ld_acc(slot + 2) / ld_acc(slot + 6));
      float o3 = (float)(ld_acc(slot + 3) / ld_acc(slot + 7));
      unsigned fl = (uD * (1.0 / 4096.0) + EPS32 > 5e-5) ? 3u : 1u; // b0=ready b1=act
      st_u32(rec + 1, __float_as_uint(o0));
      st_u32(rec + 2, __float_as_uint(o1));
      st_u32(rec + 3, __float_as_uint(o2));
      st_u32(rec + 4, __float_as_uint(o3));
      __hip_atomic_store(rec, fl, __ATOMIC_RELEASE, __HIP_MEMORY_SCOPE_AGENT);
    }
  }
  unsigned f, spins = 0;
  while (((f = ld_u32(rec)) & 1u) == 0u){
    if (++spins > (1u << 22)) break;          // safety valve: fail loud, not hung
    __builtin_amdgcn_s_sleep(2);
  }
  somf[7] = (f & 2u) ? 1.f : 0.f;
  somf[0] = __uint_as_float(ld_u32(rec + 1));
  somf[1] = __uint_as_float(ld_u32(rec + 2));
  somf[2] = __uint_as_float(ld_u32(rec + 3));
  somf[3] = __uint_as_float(ld_u32(rec + 4));
}

// ---- radix-4 register butterfly ----
#define R4REG(A, B, C, D, W1, W2, W3, SGN, Y0, Y1, Y2, Y3) {    \
  float w1y_ = (SGN)*W1.y, w2y_ = (SGN)*W2.y, w3y_ = (SGN)*W3.y;\
  float t0x = A.x + C.x, t0y = A.y + C.y;                       \
  float t1x = A.x - C.x, t1y = A.y - C.y;                       \
  float t2x = B.x + D.x, t2y = B.y + D.y;                       \
  float t3x = (SGN) * (B.y - D.y), t3y = -(SGN) * (B.x - D.x);  \
  Y0 = make_float2(t0x + t2x, t0y + t2y);                       \
  float y1x = t1x + t3x, y1y = t1y + t3y;                       \
  float y2x = t0x - t2x, y2y = t0y - t2y;                       \
  float y3x = t1x - t3x, y3y = t1y - t3y;                       \
  Y1 = make_float2(y1x*W1.x - y1y*w1y_, y1x*w1y_ + y1y*W1.x);   \
  Y2 = make_float2(y2x*W2.x - y2y*w2y_, y2x*w2y_ + y2y*W2.x);   \
  Y3 = make_float2(y3x*W3.x - y3y*w3y_, y3x*w3y_ + y3y*W3.x); }

// ---- 1024-pt Stockham radix-4 LDS stages; L = 4<<(2t); 1 bf/thread.
//      `unroll 1` (r6 spill lesson). twl = W_1024 table (768 entries). ----
__device__ __forceinline__ void r4s(float2* src, float2* dst,
                                    const float2* twl, float sgn, int cnt){
  const int tid = threadIdx.x;
  #pragma unroll 1
  for (int t = 0; t < cnt; ++t){
    const int L = 4 << (2 * t);
    const int Lm = L - 1;
    int q  = tid & Lm;
    int tb = tid - q;                         // p*L
    float2 a = src[tid];
    float2 b = src[tid + 256];
    float2 c = src[tid + 512];
    float2 d = src[tid + 768];
    float2 w1 = twl[tb];
    float2 w2 = twl[2 * tb];
    float2 w3 = twl[3 * tb];
    float2 y0, y1, y2, y3;
    R4REG(a, b, c, d, w1, w2, w3, sgn, y0, y1, y2, y3)
    int ob = q + (tb << 2);                   // q + 4*p*L
    dst[ob]         = y0;
    dst[ob + L]     = y1;
    dst[ob + 2 * L] = y2;
    dst[ob + 3 * L] = y3;
    __syncthreads();
    float2* tt = src; src = dst; dst = tt;
  }
}

// ---- wave-64 shuffle sum (f32 partials, 8-bin coverage -> exact enough) ----
__device__ __forceinline__ float wredf(float v){
  #pragma unroll
  for (int off = 32; off; off >>= 1) v += __shfl_down(v, off);
  return v;
}

// ---- reduce 9 f32 partials -> f64 atomicAdd into this round's accs slot ----
__device__ __forceinline__ void red9(float a0, float a1, float a2, float a3,
                                     float a4, float a5, float a6, float a7,
                                     float a8, float* redf, double* accs){
  const int tid = threadIdx.x, wave = tid >> 6, lane = tid & 63;
  float r;
  r = wredf(a0); if (lane == 0) redf[ 0 + wave] = r;
  r = wredf(a1); if (lane == 0) redf[ 4 + wave] = r;
  r = wredf(a2); if (lane == 0) redf[ 8 + wave] = r;
  r = wredf(a3); if (lane == 0) redf[12 + wave] = r;
  r = wredf(a4); if (lane == 0) redf[16 + wave] = r;
  r = wredf(a5); if (lane == 0) redf[20 + wave] = r;
  r = wredf(a6); if (lane == 0) redf[24 + wave] = r;
  r = wredf(a7); if (lane == 0) redf[28 + wave] = r;
  r = wredf(a8); if (lane == 0) redf[32 + wave] = r;
  __syncthreads();
  if (tid < 9){
    double s = (double)redf[tid*4+0] + (double)redf[tid*4+1]
             + (double)redf[tid*4+2] + (double)redf[tid*4+3];
    atomicAdd(&accs[tid], s);
  }
}

// ---- REAL mode update (r16): u_k[j] = rho*e^{i phi_j} with phi analytic, so
//      the whole Gauss-Seidel chain runs on real rho. ~10 ops/mode. ----
#define MODE_R(RC, OMC, AFP, AP) {                             \
  float o_ = s - (RC);                                         \
  float d_ = fj - (OMC);                                       \
  float rd_ = __builtin_amdgcn_rcpf(fmaf(2000.0f*d_, d_, 1.0f));\
  float n_ = (RR - o_) * rd_;                                  \
  float pw_ = n_ * n_;                                         \
  AFP += fj * pw_;  AP += pw_;                                 \
  float dd_ = n_ - (RC);  aD += dd_ * dd_;                     \
  (RC) = n_;  s = o_ + n_; }

#define RBIN(RHO, RRv, FJ) {                                   \
  float RR = RRv;  float fj = FJ;                              \
  float s = RHO.x + RHO.y + RHO.z + RHO.w;                     \
  MODE_R(RHO.x, om.x, aFP0, aP0)                               \
  MODE_R(RHO.y, om.y, aFP1, aP1)                               \
  MODE_R(RHO.z, om.z, aFP2, aP2)                               \
  MODE_R(RHO.w, om.w, aFP3, aP3) }

#define IT1R(RHO, RRv, FJ) { RHO = make_float4(0.f,0.f,0.f,0.f); RBIN(RHO, RRv, FJ) }

#define FOR8R(M) M(r0,R0,fj0) M(r1,R1,fj1) M(r2,R2,fj2) M(r3,R3,fj3) \
                 M(r4,R4,fj4) M(r5,R5,fj5) M(r6,R6,fj6) M(r7,R7,fj7)

// iter-5 mode-0 update (real), guarded
#define C5(RHO, RRv, FJ, CV) {                                 \
  if (act){                                                    \
    float o_ = RHO.y + RHO.z + RHO.w;                          \
    float d_ = FJ - om0;                                       \
    float rd_ = __builtin_amdgcn_rcpf(fmaf(2000.0f*d_, d_, 1.0f));\
    CV = (RRv - o_) * rd_;                                     \
  } else CV = RHO.x; }

// ==== r16: REAL-DOMAIN pipeline (DCT). fM is periodic-even around 1023.5 =>
// F[j] = 2*C_j*e^{i phi_j}, phi_j = -pi*2047*j/4096, C = DCT-II(f) real; den
// real & lam=0 => all iterates keep the per-bin phase => real iteration.
// Forward: even/odd permute -> packed 1024-pt FFT -> C_k=Re(e^{-i pi k/4096}V[k]),
// C_{2048-k}=-Im(.). Bins (k,2048-k) land on ONE thread. Inverse (derived with
// the reference's S[0]/S[2048] quirks): V'[k]=e^{+i pi k/4096}(c_k - i c_{2048-k}),
// packed 1024-pt IFFT, x_l[t] = Re z''/4096 - (-1)^t * rho_2047*cos(pi/4096)/4096.
// Nyquist: C_1024 = (ReZ0-ImZ0)*sqrt2/2; V'[1024] = sqrt2*c_1024; V'[0] = c_0.
__global__ void __attribute__((amdgpu_flat_work_group_size(256, 256),
                               amdgpu_waves_per_eu(2, 2)))
k_main(const float* __restrict__ x, unsigned* __restrict__ leaf,
       unsigned* __restrict__ root, unsigned* __restrict__ rec,
       double* __restrict__ accs, float* __restrict__ xh, float* __restrict__ xl){
  __shared__ float2 twl[768];                 // W_1024 table (6 KiB)
  __shared__ float2 bufA[1024];               // 8 KiB
  __shared__ float2 bufB[1024];               // 8 KiB
  __shared__ float redf[36];
  __shared__ float somf[8];
  __shared__ float2 vNy;                      // V'[1024]
  __shared__ float sKs;                       // c_2047 broadcast
  const int tid = threadIdx.x;
  const int b = blockIdx.x & 7, ch = blockIdx.x >> 3;
  const int gid = blockIdx.x & 7;
  const float* xc = x + (size_t)b * 2048 * 64 + ch;

  // ---- twiddles W_1024^p, p=0..767 (3/thread; rev = -p/1024 exact) ----
  #pragma unroll
  for (int i = 0; i < 3; ++i){
    int p = tid + (i << 8);
    float rev = (float)p * (-1.0f / 1024.0f);
    twl[p] = make_float2(__builtin_amdgcn_cosf(rev), __builtin_amdgcn_sinf(rev));
  }

  // ---- load f via DCT even/odd permute+pack: z[m]=v[2m]+i v[2m+1].
  //      m=tid: (f[4t],f[4t+2]); +256: (f[4t+1024],f[4t+1026]);
  //      +512: (f[2047-4t],f[2045-4t]); +768: (f[1023-4t],f[1021-4t]).
  //      Same indices are this thread's OUTPUT positions -> za..zd = stash. ----
  float2 za = make_float2(xc[(size_t)(4*tid       ) * 64], xc[(size_t)(4*tid + 2   ) * 64]);
  float2 zb = make_float2(xc[(size_t)(4*tid + 1024) * 64], xc[(size_t)(4*tid + 1026) * 64]);
  float2 zc = make_float2(xc[(size_t)(2047 - 4*tid) * 64], xc[(size_t)(2045 - 4*tid) * 64]);
  float2 zd = make_float2(xc[(size_t)(1023 - 4*tid) * 64], xc[(size_t)(1021 - 4*tid) * 64]);
  __syncthreads();                            // twl visible

  // ---- forward 1024-pt FFT: fused radix-4 L=1 from regs, then 4 LDS stages ----
  {
    float2 w1 = twl[tid], w2 = twl[2*tid], w3 = twl[3*tid];
    float2 y0, y1, y2, y3;
    R4REG(za, zb, zc, zd, w1, w2, w3, 1.0f, y0, y1, y2, y3)
    float4* d4 = reinterpret_cast<float4*>(bufA + 4 * tid);
    d4[0] = make_float4(y0.x, y0.y, y1.x, y1.y);
    d4[1] = make_float4(y2.x, y2.y, y3.x, y3.y);
  }
  __syncthreads();
  r4s(bufA, bufB, twl, 1.0f, 4);              // L=4,16,64,256 -> Z in bufA

  // ---- unpack: per c, bins (k, 2048-k): R = 2C; fj per bin ----
  float R0,R1,R2,R3,R4,R5,R6,R7, fj0,fj1,fj2,fj3,fj4,fj5,fj6,fj7;
  #define UNPK(C, RA, RB, FA, FB) {                            \
    int k = tid + ((C) << 8);                                  \
    float2 Zk = bufA[k];                                       \
    float2 Zm = bufA[(1024 - k) & 1023];                       \
    float px = 0.5f*(Zk.x + Zm.x), py = 0.5f*(Zk.y - Zm.y);    \
    float qx = 0.5f*(Zk.x - Zm.x), qy = 0.5f*(Zk.y + Zm.y);    \
    float rw = (float)k * (-1.0f / 2048.0f);                   \
    float Wx = __builtin_amdgcn_cosf(rw), Wy = __builtin_amdgcn_sinf(rw); \
    float Vx = px + Wx*qy + Wy*qx;                             \
    float Vy = py - Wx*qx + Wy*qy;                             \
    float re = (float)k * (-1.0f / 8192.0f);                   \
    float Ex = __builtin_amdgcn_cosf(re), Ey = __builtin_amdgcn_sinf(re); \
    RA = 2.0f * (Ex*Vx - Ey*Vy);                               \
    RB = -2.0f * (Ex*Vy + Ey*Vx);                              \
    FA = (float)k * (1.0f/4096.0f);                            \
    FB = (float)(2048 - k) * (1.0f/4096.0f); }
  UNPK(0, R0, R1, fj0, fj1)
  UNPK(1, R2, R3, fj2, fj3)
  UNPK(2, R4, R5, fj4, fj5)
  UNPK(3, R6, R7, fj6, fj7)
  if (tid == 0){                              // k=0 pair is (bin0, bin1024)
    float2 Z0 = bufA[0];
    R1 = 1.41421356237f * (Z0.x - Z0.y);      // sqrt2*V[1024]; V[1024]=ReZ0-ImZ0
    fj1 = 0.25f;
  }

  float4 r0, r1, r2, r3, r4, r5, r6, r7;      // rho[mode] per bin
  float4 om = make_float4(0.0f, 0.125f, 0.25f, 0.375f);

  // iter 1 (rho starts 0) — pure register, real
  {
    float aFP0=0,aFP1=0,aFP2=0,aFP3=0,aP0=0,aP1=0,aP2=0,aP3=0,aD=0;
    FOR8R(IT1R)
    red9(aFP0,aFP1,aFP2,aFP3,aP0,aP1,aP2,aP3,aD, redf, accs);
  }

  // ---- iters 2..4: tree barrier + record-broadcast omega ----
  bool active = true;
  #pragma unroll 1
  for (int it = 0; it < 3; ++it){
    __syncthreads();
    if (tid == 0)
      tree_sync_omega(leaf + it * 256, root + it * 32, rec + it * 32,
                      accs + it * 16, somf, gid);
    __syncthreads();
    if (active){
      if (somf[7] != 0.0f){
        om.x = somf[0]; om.y = somf[1]; om.z = somf[2]; om.w = somf[3];
      } else active = false;
    }
    if (active){
      float aFP0=0,aFP1=0,aFP2=0,aFP3=0,aP0=0,aP1=0,aP2=0,aP3=0,aD=0;
      FOR8R(RBIN)
      red9(aFP0,aFP1,aFP2,aFP3,aP0,aP1,aP2,aP3,aD, redf, accs + (it + 1) * 16);
    }
  }
  __syncthreads();
  if (tid == 0)
    tree_sync_omega(leaf + 3 * 256, root + 3 * 32, rec + 3 * 32,
                    accs + 3 * 16, somf, gid);
  __syncthreads();

  // ---- iter-5 mode-0 (real) -> c values; V' -> bufA; packed IFFT ----
  {
    bool act = active && (somf[7] != 0.0f);
    float om0 = somf[0];
    float c0, c1, c2, c3, c4, c5, c6, c7;
    C5(r0, R0, fj0, c0)  C5(r1, R1, fj1, c1)
    C5(r2, R2, fj2, c2)  C5(r3, R3, fj3, c3)
    C5(r4, R4, fj4, c4)  C5(r5, R5, fj5, c5)
    C5(r6, R6, fj6, c6)  C5(r7, R7, fj7, c7)
    if (tid == 1) sKs = c1;                   // bin 2047 (pair of k=1)
    if (tid == 0) vNy = make_float2(1.41421356237f * c1, 0.0f); // V'[1024]
    // V'[k] = e^{+i pi k/4096} (c_k - i c_{2048-k})
    #define VPW(C, CA, CB) {                                   \
      int k = tid + ((C) << 8);                                \
      float rg = (float)k * (1.0f / 8192.0f);                  \
      float Gx = __builtin_amdgcn_cosf(rg), Gy = __builtin_amdgcn_sinf(rg); \
      bufA[k] = make_float2(Gx*(CA) + Gy*(CB), Gy*(CA) - Gx*(CB)); }
    VPW(0, c0, c1)  VPW(1, c2, c3)  VPW(2, c4, c5)  VPW(3, c6, c7)
    if (tid == 0) bufA[0] = make_float2(c0, 0.0f);   // V'[0] = c_0 (real)
  }
  __syncthreads();
  // Z''[q] = E + iO; E = V'[q]+conj(V'[1024-q]); O = (V'[q]-conj(V'[1024-q]))*e^{+2pi i q/2048}
  float2 p0, p1, p2, p3;
  #define ZB(C, ZV) {                                          \
    int q = tid + ((C) << 8);                                  \
    float2 Vq = bufA[q];                                       \
    float2 Vm = (q == 0) ? vNy : bufA[1024 - q];               \
    Vm.y = -Vm.y;                                              \
    float Ex_ = Vq.x + Vm.x, Ey_ = Vq.y + Vm.y;                \
    float Dx = Vq.x - Vm.x,  Dy = Vq.y - Vm.y;                 \
    float rw = (float)q * (1.0f / 2048.0f);                    \
    float Wx = __builtin_amdgcn_cosf(rw), Wy = __builtin_amdgcn_sinf(rw); \
    float Ox = Dx*Wx - Dy*Wy;                                  \
    float Oy = Dx*Wy + Dy*Wx;                                  \
    ZV = make_float2(Ex_ - Oy, Ey_ + Ox); }
  ZB(0, p0)  ZB(1, p1)  ZB(2, p2)  ZB(3, p3)
  {                                           // fused inverse radix-4 L=1
    float2 w1 = twl[tid], w2 = twl[2*tid], w3 = twl[3*tid];
    float2 y0, y1, y2, y3;
    R4REG(p0, p1, p2, p3, w1, w2, w3, -1.0f, y0, y1, y2, y3)
    float4* d4 = reinterpret_cast<float4*>(bufB + 4 * tid);
    d4[0] = make_float4(y0.x, y0.y, y1.x, y1.y);
    d4[1] = make_float4(y2.x, y2.y, y3.x, y3.y);
  }
  __syncthreads();
  r4s(bufB, bufA, twl, -1.0f, 3);             // L=4,16,64 -> result in bufA

  // ---- fused last inverse stage (L=256, tb=0, twiddle-free) + epilogue ----
  {
    float2 a = bufA[tid], bb = bufA[tid + 256];
    float2 c = bufA[tid + 512], d = bufA[tid + 768];
    float t0x = a.x + c.x, t0y = a.y + c.y;
    float t1x = a.x - c.x, t1y = a.y - c.y;
    float t2x = bb.x + d.x, t2y = bb.y + d.y;
    float t3x = -(bb.y - d.y), t3y = (bb.x - d.x);   // sgn=-1
    float2 y0 = make_float2(t0x + t2x, t0y + t2y);   // z''[tid]
    float2 y1 = make_float2(t1x + t3x, t1y + t3y);   // z''[tid+256]
    float2 y2 = make_float2(t0x - t2x, t0y - t2y);   // z''[tid+512]
    float2 y3 = make_float2(t1x - t3x, t1y - t3y);   // z''[tid+768]
    const float sc = 1.0f / 4096.0f;
    float kc = sKs * (0.99999970586f * sc);   // rho_2047*cos(pi/4096)/4096
    // x_l[t] = Re(z'')/4096 - (-1)^t * kc  (even t: -kc, odd t: +kc)
    #define OUT2(YV, T0, T1, KS, ZS) {                         \
      size_t oa = ((size_t)(b * 2048 + (T0))) * 64 + ch;       \
      size_t ob = ((size_t)(b * 2048 + (T1))) * 64 + ch;       \
      float l0 = YV.x * sc KS kc;                              \
      float l1 = YV.y * sc KS kc;                              \
      xl[oa] = l0;  xh[oa] = ZS.x - l0;                        \
      xl[ob] = l1;  xh[ob] = ZS.y - l1; }
    OUT2(y0, 4*tid,        4*tid + 2,    -, za)      // even t
    OUT2(y1, 4*tid + 1024, 4*tid + 1026, -, zb)      // even t
    OUT2(y2, 2047 - 4*tid, 2045 - 4*tid, +, zc)      // odd t
    OUT2(y3, 1023 - 4*tid, 1021 - 4*tid, +, zd)      // odd t
  }
}

extern "C" void kernel_launch(void* const* d_in, const int* in_sizes, int n_in,
                              void* d_out, int out_size, void* d_ws, size_t ws_size,
                              hipStream_t stream){
  const float* x = (const float*)d_in[0];
  float* out_xh = (float*)d_out;
  float* out_xl = out_xh + (size_t)8 * 2048 * 64;

  // ws: leaf 4x8x128B = 4096 | root 4x128B | rec 4x128B | accs 4x128B
  char* ws = (char*)d_ws;
  unsigned* leaf = (unsigned*)ws;
  unsigned* root = (unsigned*)(ws + 4096);
  unsigned* rec  = (unsigned*)(ws + 4608);
  double*   accs = (double*)  (ws + 5120);

  hipMemsetAsync(ws, 0, 5632, stream);
  k_main<<<NBLK, 256, 0, stream>>>(x, leaf, root, rec, accs, out_xh, out_xl);
}

// Round 17
// 113.017 us; speedup vs baseline: 1.2645x; 1.0502x over previous
//
#include <hip/hip_runtime.h>
#include <math.h>

#define NBLK 512
#define EPS32 1.1920928955078125e-07

// agent-scope atomics: always at the coherent point (LLC)
__device__ __forceinline__ double ld_acc(const double* p){
  return __hip_atomic_load(p, __ATOMIC_RELAXED, __HIP_MEMORY_SCOPE_AGENT);
}
__device__ __forceinline__ unsigned ld_u32(const unsigned* p){
  return __hip_atomic_load(p, __ATOMIC_RELAXED, __HIP_MEMORY_SCOPE_AGENT);
}
__device__ __forceinline__ void st_u32(unsigned* p, unsigned v){
  __hip_atomic_store(p, v, __ATOMIC_RELAXED, __HIP_MEMORY_SCOPE_AGENT);
}

// ---- r17: de-contended sync fabric. Arrival: 64 leaves (8 blocks) -> 8 mids
// -> root (max 8 same-line RMWs at any level; was 64). Deposits are sharded
// into accs[gid3] (8 lines; was 4608 RMWs on 2 lines). The mid-last FOLDS its
// shard into racc (9 adds) and bumps root with ACQ_REL (release orders folds;
// acquire on root-last makes them visible). Root-last reads racc only,
// computes omega once, publishes to 8 replicated rec lines; each block polls
// its gid3 line (64 pollers/line; was 512 on one). tid0-only; caller's
// __syncthreads drains this block's deposits before arrival (proven r14-r16).
__device__ void tree_sync_omega(unsigned* leafL, unsigned* midL, unsigned* rootL,
                                unsigned* recL, const double* accsG,
                                double* racc, float* somf, int l6, int g3){
  unsigned o = __hip_atomic_fetch_add(leafL + (size_t)l6 * 32, 1u,
                                      __ATOMIC_RELAXED, __HIP_MEMORY_SCOPE_AGENT);
  if (o == 7u){
    int m = l6 & 7;
    unsigned om_ = __hip_atomic_fetch_add(midL + (size_t)m * 32, 1u,
                                          __ATOMIC_RELAXED, __HIP_MEMORY_SCOPE_AGENT);
    if (om_ == 7u){                           // mid-last: fold shard m
      const double* ag = accsG + (size_t)m * 16;
      double v0 = ld_acc(ag+0), v1 = ld_acc(ag+1), v2 = ld_acc(ag+2);
      double v3 = ld_acc(ag+3), v4 = ld_acc(ag+4), v5 = ld_acc(ag+5);
      double v6 = ld_acc(ag+6), v7 = ld_acc(ag+7), v8 = ld_acc(ag+8);
      atomicAdd(racc+0, v0); atomicAdd(racc+1, v1); atomicAdd(racc+2, v2);
      atomicAdd(racc+3, v3); atomicAdd(racc+4, v4); atomicAdd(racc+5, v5);
      atomicAdd(racc+6, v6); atomicAdd(racc+7, v7); atomicAdd(racc+8, v8);
      unsigned orr = __hip_atomic_fetch_add(rootL, 1u,
                                            __ATOMIC_ACQ_REL, __HIP_MEMORY_SCOPE_AGENT);
      if (orr == 7u){                         // root-last: compute + publish x8
        double uD = ld_acc(racc + 8);
        float o0 = (float)(ld_acc(racc+0) / ld_acc(racc+4));
        float o1 = (float)(ld_acc(racc+1) / ld_acc(racc+5));
        float o2 = (float)(ld_acc(racc+2) / ld_acc(racc+6));
        float o3 = (float)(ld_acc(racc+3) / ld_acc(racc+7));
        unsigned fl = (uD * (1.0 / 4096.0) + EPS32 > 5e-5) ? 3u : 1u;
        #pragma unroll
        for (int r = 0; r < 8; ++r){
          unsigned* rl = recL + (size_t)r * 32;
          st_u32(rl + 1, __float_as_uint(o0));
          st_u32(rl + 2, __float_as_uint(o1));
          st_u32(rl + 3, __float_as_uint(o2));
          st_u32(rl + 4, __float_as_uint(o3));
        }
        #pragma unroll
        for (int r = 0; r < 8; ++r)           // release: payloads before flags
          __hip_atomic_store(recL + (size_t)r * 32, fl,
                             __ATOMIC_RELEASE, __HIP_MEMORY_SCOPE_AGENT);
      }
    }
  }
  unsigned* myrec = recL + (size_t)g3 * 32;
  unsigned f, spins = 0;
  while (((f = ld_u32(myrec)) & 1u) == 0u){
    if (++spins > (1u << 22)) break;          // safety valve: fail loud, not hung
    __builtin_amdgcn_s_sleep(1);
  }
  somf[7] = (f & 2u) ? 1.f : 0.f;
  somf[0] = __uint_as_float(ld_u32(myrec + 1));  // issued after flag returns;
  somf[1] = __uint_as_float(ld_u32(myrec + 2));  // writer's release ordered
  somf[2] = __uint_as_float(ld_u32(myrec + 3));  // payloads first (r14-proven)
  somf[3] = __uint_as_float(ld_u32(myrec + 4));
}

// ---- radix-4 register butterfly ----
#define R4REG(A, B, C, D, W1, W2, W3, SGN, Y0, Y1, Y2, Y3) {    \
  float w1y_ = (SGN)*W1.y, w2y_ = (SGN)*W2.y, w3y_ = (SGN)*W3.y;\
  float t0x = A.x + C.x, t0y = A.y + C.y;                       \
  float t1x = A.x - C.x, t1y = A.y - C.y;                       \
  float t2x = B.x + D.x, t2y = B.y + D.y;                       \
  float t3x = (SGN) * (B.y - D.y), t3y = -(SGN) * (B.x - D.x);  \
  Y0 = make_float2(t0x + t2x, t0y + t2y);                       \
  float y1x = t1x + t3x, y1y = t1y + t3y;                       \
  float y2x = t0x - t2x, y2y = t0y - t2y;                       \
  float y3x = t1x - t3x, y3y = t1y - t3y;                       \
  Y1 = make_float2(y1x*W1.x - y1y*w1y_, y1x*w1y_ + y1y*W1.x);   \
  Y2 = make_float2(y2x*W2.x - y2y*w2y_, y2x*w2y_ + y2y*W2.x);   \
  Y3 = make_float2(y3x*W3.x - y3y*w3y_, y3x*w3y_ + y3y*W3.x); }

// ---- 1024-pt Stockham radix-4 LDS stages; L = 4<<(2t); 1 bf/thread.
//      `unroll 1` (r6 spill lesson). twl = W_1024 table (768 entries). ----
__device__ __forceinline__ void r4s(float2* src, float2* dst,
                                    const float2* twl, float sgn, int cnt){
  const int tid = threadIdx.x;
  #pragma unroll 1
  for (int t = 0; t < cnt; ++t){
    const int L = 4 << (2 * t);
    const int Lm = L - 1;
    int q  = tid & Lm;
    int tb = tid - q;                         // p*L
    float2 a = src[tid];
    float2 b = src[tid + 256];
    float2 c = src[tid + 512];
    float2 d = src[tid + 768];
    float2 w1 = twl[tb];
    float2 w2 = twl[2 * tb];
    float2 w3 = twl[3 * tb];
    float2 y0, y1, y2, y3;
    R4REG(a, b, c, d, w1, w2, w3, sgn, y0, y1, y2, y3)
    int ob = q + (tb << 2);                   // q + 4*p*L
    dst[ob]         = y0;
    dst[ob + L]     = y1;
    dst[ob + 2 * L] = y2;
    dst[ob + 3 * L] = y3;
    __syncthreads();
    float2* tt = src; src = dst; dst = tt;
  }
}

// ---- wave-64 shuffle sum (f32 partials, 8-bin coverage -> exact enough) ----
__device__ __forceinline__ float wredf(float v){
  #pragma unroll
  for (int off = 32; off; off >>= 1) v += __shfl_down(v, off);
  return v;
}

// ---- reduce 9 f32 partials -> f64 atomicAdd into this round's gid shard ----
__device__ __forceinline__ void red9(float a0, float a1, float a2, float a3,
                                     float a4, float a5, float a6, float a7,
                                     float a8, float* redf, double* accsG){
  const int tid = threadIdx.x, wave = tid >> 6, lane = tid & 63;
  float r;
  r = wredf(a0); if (lane == 0) redf[ 0 + wave] = r;
  r = wredf(a1); if (lane == 0) redf[ 4 + wave] = r;
  r = wredf(a2); if (lane == 0) redf[ 8 + wave] = r;
  r = wredf(a3); if (lane == 0) redf[12 + wave] = r;
  r = wredf(a4); if (lane == 0) redf[16 + wave] = r;
  r = wredf(a5); if (lane == 0) redf[20 + wave] = r;
  r = wredf(a6); if (lane == 0) redf[24 + wave] = r;
  r = wredf(a7); if (lane == 0) redf[28 + wave] = r;
  r = wredf(a8); if (lane == 0) redf[32 + wave] = r;
  __syncthreads();
  if (tid < 9){
    double s = (double)redf[tid*4+0] + (double)redf[tid*4+1]
             + (double)redf[tid*4+2] + (double)redf[tid*4+3];
    atomicAdd(&accsG[tid], s);
  }
}

// ---- REAL mode update (r16): ~10 ops/mode, rcp divide (r15) ----
#define MODE_R(RC, OMC, AFP, AP) {                             \
  float o_ = s - (RC);                                         \
  float d_ = fj - (OMC);                                       \
  float rd_ = __builtin_amdgcn_rcpf(fmaf(2000.0f*d_, d_, 1.0f));\
  float n_ = (RR - o_) * rd_;                                  \
  float pw_ = n_ * n_;                                         \
  AFP += fj * pw_;  AP += pw_;                                 \
  float dd_ = n_ - (RC);  aD += dd_ * dd_;                     \
  (RC) = n_;  s = o_ + n_; }

#define RBIN(RHO, RRv, FJ) {                                   \
  float RR = RRv;  float fj = FJ;                              \
  float s = RHO.x + RHO.y + RHO.z + RHO.w;                     \
  MODE_R(RHO.x, om.x, aFP0, aP0)                               \
  MODE_R(RHO.y, om.y, aFP1, aP1)                               \
  MODE_R(RHO.z, om.z, aFP2, aP2)                               \
  MODE_R(RHO.w, om.w, aFP3, aP3) }

#define IT1R(RHO, RRv, FJ) { RHO = make_float4(0.f,0.f,0.f,0.f); RBIN(RHO, RRv, FJ) }

#define FOR8R(M) M(r0,R0,fj0) M(r1,R1,fj1) M(r2,R2,fj2) M(r3,R3,fj3) \
                 M(r4,R4,fj4) M(r5,R5,fj5) M(r6,R6,fj6) M(r7,R7,fj7)

// iter-5 mode-0 update (real), guarded
#define C5(RHO, RRv, FJ, CV) {                                 \
  if (act){                                                    \
    float o_ = RHO.y + RHO.z + RHO.w;                          \
    float d_ = FJ - om0;                                       \
    float rd_ = __builtin_amdgcn_rcpf(fmaf(2000.0f*d_, d_, 1.0f));\
    CV = (RRv - o_) * rd_;                                     \
  } else CV = RHO.x; }

// ==== r17 = r16 real-domain pipeline + de-contended sync + fwd-last-stage
// fusion (L=256 stage has tb=0 => twiddle-free => computed in regs; UNPK reads
// only the 4 mirrors from LDS). ====
__global__ void __attribute__((amdgpu_flat_work_group_size(256, 256),
                               amdgpu_waves_per_eu(2, 2)))
k_main(const float* __restrict__ x, unsigned* __restrict__ leaf,
       unsigned* __restrict__ mid, unsigned* __restrict__ root,
       unsigned* __restrict__ rec, double* __restrict__ racc,
       double* __restrict__ accs, float* __restrict__ xh, float* __restrict__ xl){
  __shared__ float2 twl[768];                 // W_1024 table (6 KiB)
  __shared__ float2 bufA[1024];               // 8 KiB
  __shared__ float2 bufB[1024];               // 8 KiB
  __shared__ float redf[36];
  __shared__ float somf[8];
  __shared__ float2 vNy;                      // V'[1024]
  __shared__ float sKs;                       // c_2047 broadcast
  const int tid = threadIdx.x;
  const int b = blockIdx.x & 7, ch = blockIdx.x >> 3;
  const int l6 = blockIdx.x & 63, g3 = blockIdx.x & 7;
  const float* xc = x + (size_t)b * 2048 * 64 + ch;

  // ---- twiddles W_1024^p, p=0..767 (3/thread; rev = -p/1024 exact) ----
  #pragma unroll
  for (int i = 0; i < 3; ++i){
    int p = tid + (i << 8);
    float rev = (float)p * (-1.0f / 1024.0f);
    twl[p] = make_float2(__builtin_amdgcn_cosf(rev), __builtin_amdgcn_sinf(rev));
  }

  // ---- load f via DCT even/odd permute+pack (za..zd double as output stash) ----
  float2 za = make_float2(xc[(size_t)(4*tid       ) * 64], xc[(size_t)(4*tid + 2   ) * 64]);
  float2 zb = make_float2(xc[(size_t)(4*tid + 1024) * 64], xc[(size_t)(4*tid + 1026) * 64]);
  float2 zc = make_float2(xc[(size_t)(2047 - 4*tid) * 64], xc[(size_t)(2045 - 4*tid) * 64]);
  float2 zd = make_float2(xc[(size_t)(1023 - 4*tid) * 64], xc[(size_t)(1021 - 4*tid) * 64]);
  __syncthreads();                            // twl visible

  // ---- forward 1024-pt FFT: fused radix-4 L=1 (regs) + 3 LDS stages +
  //      fused last stage (L=256, tb=0, twiddle-free) kept in registers ----
  {
    float2 w1 = twl[tid], w2 = twl[2*tid], w3 = twl[3*tid];
    float2 y0, y1, y2, y3;
    R4REG(za, zb, zc, zd, w1, w2, w3, 1.0f, y0, y1, y2, y3)
    float4* d4 = reinterpret_cast<float4*>(bufA + 4 * tid);
    d4[0] = make_float4(y0.x, y0.y, y1.x, y1.y);
    d4[1] = make_float4(y2.x, y2.y, y3.x, y3.y);
  }
  __syncthreads();
  r4s(bufA, bufB, twl, 1.0f, 3);              // L=4,16,64 -> result in bufB
  float2 Zs0, Zs1, Zs2, Zs3;                  // Z[tid + {0,256,512,768}]
  {
    float2 a = bufB[tid], b2 = bufB[tid + 256];
    float2 c2 = bufB[tid + 512], d2 = bufB[tid + 768];
    float t0x = a.x + c2.x, t0y = a.y + c2.y;
    float t1x = a.x - c2.x, t1y = a.y - c2.y;
    float t2x = b2.x + d2.x, t2y = b2.y + d2.y;
    float t3x = (b2.y - d2.y), t3y = -(b2.x - d2.x);   // fwd -i*(b-d)
    Zs0 = make_float2(t0x + t2x, t0y + t2y);
    Zs1 = make_float2(t1x + t3x, t1y + t3y);
    Zs2 = make_float2(t0x - t2x, t0y - t2y);
    Zs3 = make_float2(t1x - t3x, t1y - t3y);
    bufA[tid]       = Zs0;  bufA[tid + 256] = Zs1;
    bufA[tid + 512] = Zs2;  bufA[tid + 768] = Zs3;
  }
  __syncthreads();

  // ---- unpack: per c, bins (k, 2048-k): R = 2C; own Z from regs ----
  float R0,R1,R2,R3,R4,R5,R6,R7, fj0,fj1,fj2,fj3,fj4,fj5,fj6,fj7;
  #define UNPK(C, ZS, RA, RB, FA, FB) {                        \
    int k = tid + ((C) << 8);                                  \
    float2 Zk = ZS;                                            \
    float2 Zm = bufA[(1024 - k) & 1023];                       \
    float px = 0.5f*(Zk.x + Zm.x), py = 0.5f*(Zk.y - Zm.y);    \
    float qx = 0.5f*(Zk.x - Zm.x), qy = 0.5f*(Zk.y + Zm.y);    \
    float rw = (float)k * (-1.0f / 2048.0f);                   \
    float Wx = __builtin_amdgcn_cosf(rw), Wy = __builtin_amdgcn_sinf(rw); \
    float Vx = px + Wx*qy + Wy*qx;                             \
    float Vy = py - Wx*qx + Wy*qy;                             \
    float re = (float)k * (-1.0f / 8192.0f);                   \
    float Ex = __builtin_amdgcn_cosf(re), Ey = __builtin_amdgcn_sinf(re); \
    RA = 2.0f * (Ex*Vx - Ey*Vy);                               \
    RB = -2.0f * (Ex*Vy + Ey*Vx);                              \
    FA = (float)k * (1.0f/4096.0f);                            \
    FB = (float)(2048 - k) * (1.0f/4096.0f); }
  UNPK(0, Zs0, R0, R1, fj0, fj1)
  UNPK(1, Zs1, R2, R3, fj2, fj3)
  UNPK(2, Zs2, R4, R5, fj4, fj5)
  UNPK(3, Zs3, R6, R7, fj6, fj7)
  if (tid == 0){                              // k=0 pair is (bin0, bin1024)
    R1 = 1.41421356237f * (Zs0.x - Zs0.y);    // sqrt2*V[1024]
    fj1 = 0.25f;
  }

  float4 r0, r1, r2, r3, r4, r5, r6, r7;      // rho[mode] per bin
  float4 om = make_float4(0.0f, 0.125f, 0.25f, 0.375f);

  // iter 1 (rho starts 0) — pure register, real
  {
    float aFP0=0,aFP1=0,aFP2=0,aFP3=0,aP0=0,aP1=0,aP2=0,aP3=0,aD=0;
    FOR8R(IT1R)
    red9(aFP0,aFP1,aFP2,aFP3,aP0,aP1,aP2,aP3,aD, redf, accs + (size_t)g3*16);
  }

  // ---- iters 2..4: tree barrier + replicated-record omega ----
  bool active = true;
  #pragma unroll 1
  for (int it = 0; it < 3; ++it){
    __syncthreads();                          // drain this block's deposits
    if (tid == 0)
      tree_sync_omega(leaf + (size_t)it*64*32, mid + (size_t)it*8*32,
                      root + (size_t)it*32, rec + (size_t)it*8*32,
                      accs + (size_t)it*128, racc + (size_t)it*16,
                      somf, l6, g3);
    __syncthreads();                          // somf visible to all
    if (active){
      if (somf[7] != 0.0f){
        om.x = somf[0]; om.y = somf[1]; om.z = somf[2]; om.w = somf[3];
      } else active = false;
    }
    if (active){
      float aFP0=0,aFP1=0,aFP2=0,aFP3=0,aP0=0,aP1=0,aP2=0,aP3=0,aD=0;
      FOR8R(RBIN)
      red9(aFP0,aFP1,aFP2,aFP3,aP0,aP1,aP2,aP3,aD, redf,
           accs + (size_t)(it + 1)*128 + (size_t)g3*16);
    }
  }
  __syncthreads();
  if (tid == 0)
    tree_sync_omega(leaf + (size_t)3*64*32, mid + (size_t)3*8*32,
                    root + (size_t)3*32, rec + (size_t)3*8*32,
                    accs + (size_t)3*128, racc + (size_t)3*16,
                    somf, l6, g3);
  __syncthreads();

  // ---- iter-5 mode-0 (real) -> c values; V' -> bufA; packed IFFT ----
  {
    bool act = active && (somf[7] != 0.0f);
    float om0 = somf[0];
    float c0, c1, c2, c3, c4, c5, c6, c7;
    C5(r0, R0, fj0, c0)  C5(r1, R1, fj1, c1)
    C5(r2, R2, fj2, c2)  C5(r3, R3, fj3, c3)
    C5(r4, R4, fj4, c4)  C5(r5, R5, fj5, c5)
    C5(r6, R6, fj6, c6)  C5(r7, R7, fj7, c7)
    if (tid == 1) sKs = c1;                   // bin 2047 (pair of k=1)
    if (tid == 0) vNy = make_float2(1.41421356237f * c1, 0.0f); // V'[1024]
    // V'[k] = e^{+i pi k/4096} (c_k - i c_{2048-k})
    #define VPW(C, CA, CB) {                                   \
      int k = tid + ((C) << 8);                                \
      float rg = (float)k * (1.0f / 8192.0f);                  \
      float Gx = __builtin_amdgcn_cosf(rg), Gy = __builtin_amdgcn_sinf(rg); \
      bufA[k] = make_float2(Gx*(CA) + Gy*(CB), Gy*(CA) - Gx*(CB)); }
    VPW(0, c0, c1)  VPW(1, c2, c3)  VPW(2, c4, c5)  VPW(3, c6, c7)
    if (tid == 0) bufA[0] = make_float2(c0, 0.0f);   // V'[0] = c_0 (real)
  }
  __syncthreads();
  // Z''[q] = E + iO; E = V'[q]+conj(V'[1024-q]); O = (V'[q]-conj(V'[1024-q]))*W
  float2 p0, p1, p2, p3;
  #define ZB(C, ZV) {                                          \
    int q = tid + ((C) << 8);                                  \
    float2 Vq = bufA[q];                                       \
    float2 Vm = (q == 0) ? vNy : bufA[1024 - q];               \
    Vm.y = -Vm.y;                                              \
    float Ex_ = Vq.x + Vm.x, Ey_ = Vq.y + Vm.y;                \
    float Dx = Vq.x - Vm.x,  Dy = Vq.y - Vm.y;                 \
    float rw = (float)q * (1.0f / 2048.0f);                    \
    float Wx = __builtin_amdgcn_cosf(rw), Wy = __builtin_amdgcn_sinf(rw); \
    float Ox = Dx*Wx - Dy*Wy;                                  \
    float Oy = Dx*Wy + Dy*Wx;                                  \
    ZV = make_float2(Ex_ - Oy, Ey_ + Ox); }
  ZB(0, p0)  ZB(1, p1)  ZB(2, p2)  ZB(3, p3)
  {                                           // fused inverse radix-4 L=1
    float2 w1 = twl[tid], w2 = twl[2*tid], w3 = twl[3*tid];
    float2 y0, y1, y2, y3;
    R4REG(p0, p1, p2, p3, w1, w2, w3, -1.0f, y0, y1, y2, y3)
    float4* d4 = reinterpret_cast<float4*>(bufB + 4 * tid);
    d4[0] = make_float4(y0.x, y0.y, y1.x, y1.y);
    d4[1] = make_float4(y2.x, y2.y, y3.x, y3.y);
  }
  __syncthreads();
  r4s(bufB, bufA, twl, -1.0f, 3);             // L=4,16,64 -> result in bufA

  // ---- fused last inverse stage (L=256, tb=0, twiddle-free) + epilogue ----
  {
    float2 a = bufA[tid], bb = bufA[tid + 256];
    float2 c = bufA[tid + 512], d = bufA[tid + 768];
    float t0x = a.x + c.x, t0y = a.y + c.y;
    float t1x = a.x - c.x, t1y = a.y - c.y;
    float t2x = bb.x + d.x, t2y = bb.y + d.y;
    float t3x = -(bb.y - d.y), t3y = (bb.x - d.x);   // sgn=-1
    float2 y0 = make_float2(t0x + t2x, t0y + t2y);   // z''[tid]
    float2 y1 = make_float2(t1x + t3x, t1y + t3y);   // z''[tid+256]
    float2 y2 = make_float2(t0x - t2x, t0y - t2y);   // z''[tid+512]
    float2 y3 = make_float2(t1x - t3x, t1y - t3y);   // z''[tid+768]
    const float sc = 1.0f / 4096.0f;
    float kc = sKs * (0.99999970586f * sc);   // rho_2047*cos(pi/4096)/4096
    // x_l[t] = Re(z'')/4096 - (-1)^t * kc
    #define OUT2(YV, T0, T1, KS, ZS) {                         \
      size_t oa = ((size_t)(b * 2048 + (T0))) * 64 + ch;       \
      size_t ob = ((size_t)(b * 2048 + (T1))) * 64 + ch;       \
      float l0 = YV.x * sc KS kc;                              \
      float l1 = YV.y * sc KS kc;                              \
      xl[oa] = l0;  xh[oa] = ZS.x - l0;                        \
      xl[ob] = l1;  xh[ob] = ZS.y - l1; }
    OUT2(y0, 4*tid,        4*tid + 2,    -, za)      // even t
    OUT2(y1, 4*tid + 1024, 4*tid + 1026, -, zb)      // even t
    OUT2(y2, 2047 - 4*tid, 2045 - 4*tid, +, zc)      // odd t
    OUT2(y3, 1023 - 4*tid, 1021 - 4*tid, +, zd)      // odd t
  }
}

extern "C" void kernel_launch(void* const* d_in, const int* in_sizes, int n_in,
                              void* d_out, int out_size, void* d_ws, size_t ws_size,
                              hipStream_t stream){
  const float* x = (const float*)d_in[0];
  float* out_xh = (float*)d_out;
  float* out_xl = out_xh + (size_t)8 * 2048 * 64;

  // ws layout (all zeroed each launch; strides of 128 B per line):
  //   leaf: 4 rounds x 64 x 128B = 32768 @ 0
  //   mid:  4 x 8 x 128B         =  4096 @ 32768
  //   root: 4 x 128B             =   512 @ 36864
  //   racc: 4 x 128B (9 dbl)     =   512 @ 37376
  //   rec:  4 x 8 x 128B         =  4096 @ 37888
  //   accs: 4 x 8 x 128B         =  4096 @ 41984
  char* ws = (char*)d_ws;
  unsigned* leaf = (unsigned*)ws;
  unsigned* mid  = (unsigned*)(ws + 32768);
  unsigned* root = (unsigned*)(ws + 36864);
  double*   racc = (double*)  (ws + 37376);
  unsigned* rec  = (unsigned*)(ws + 37888);
  double*   accs = (double*)  (ws + 41984);

  hipMemsetAsync(ws, 0, 46080, stream);
  k_main<<<NBLK, 256, 0, stream>>>(x, leaf, mid, root, rec, racc, accs,
                                   out_xh, out_xl);
}